// Round 1
// baseline (269.708 us; speedup 1.0000x reference)
//
#include <hip/hip_runtime.h>
#include <cstdint>
#include <cstddef>

// Problem constants (from setup_inputs)
#define BB 4
#define NN 20000
#define KK 16
#define MM 9
#define CC 64
#define OO 64
#define BN (BB*NN)          // 80000 nodes
#define MC (MM*CC)          // 576 = flattened reduction dim

typedef __bf16 bf16x8 __attribute__((ext_vector_type(8)));
typedef float  f32x4  __attribute__((ext_vector_type(4)));
typedef unsigned short ushort_t;

__device__ __forceinline__ ushort_t f2bf(float f) {
    unsigned int u = __float_as_uint(f);
    u = (u + 0x7fffu + ((u >> 16) & 1u)) >> 16;   // round-to-nearest-even
    return (ushort_t)u;
}

// ---------------------------------------------------------------------------
// Kernel 1: ux[b,n,m] = u[m]·x[b,n], vx[b,n,m] = v[m]·x[b,n];
//           plus W repack: wfb[o][m*64+c] = bf16(W[m][o][c])  (B-operand layout)
// ---------------------------------------------------------------------------
__global__ __launch_bounds__(256) void precompute_kernel(
    const float* __restrict__ x, const float* __restrict__ W,
    const float* __restrict__ u, const float* __restrict__ v,
    float* __restrict__ ux, float* __restrict__ vx, ushort_t* __restrict__ wfb)
{
    if (blockIdx.x < 313) {
        int node = blockIdx.x * 256 + threadIdx.x;
        if (node >= BN) return;
        float au[MM], av[MM];
        #pragma unroll
        for (int m = 0; m < MM; ++m) { au[m] = 0.f; av[m] = 0.f; }
        const float4* xr = (const float4*)(x + (size_t)node * CC);
        #pragma unroll 4
        for (int c4 = 0; c4 < CC/4; ++c4) {
            float4 xv = xr[c4];
            #pragma unroll
            for (int m = 0; m < MM; ++m) {
                const float* um = u + m*CC + c4*4;   // uniform -> scalar loads
                const float* vm = v + m*CC + c4*4;
                au[m] += um[0]*xv.x + um[1]*xv.y + um[2]*xv.z + um[3]*xv.w;
                av[m] += vm[0]*xv.x + vm[1]*xv.y + vm[2]*xv.z + vm[3]*xv.w;
            }
        }
        #pragma unroll
        for (int m = 0; m < MM; ++m) {
            ux[(size_t)node*MM + m] = au[m];
            vx[(size_t)node*MM + m] = av[m];
        }
    } else {
        // W: [M][O][C] -> wfb: [O][M*C] bf16 (so B-fragment k-runs are contiguous)
        for (int i = threadIdx.x; i < MM*OO*CC; i += 256) {
            int m = i >> 12;            // /4096
            int rem = i & 4095;
            int o = rem >> 6;
            int c = rem & 63;
            wfb[(size_t)o*MC + m*CC + c] = f2bf(W[i]);
        }
    }
}

// ---------------------------------------------------------------------------
// Kernel 2: per-node fused mask / softmax (over M) / neighbor aggregation.
// One wave per node, lane = channel c. q broadcast via v_readlane (VALU pipe,
// avoids LDS-broadcast bottleneck). inv_deg folded into q. s written as bf16.
// ---------------------------------------------------------------------------
__global__ __launch_bounds__(256) void stage1_kernel(
    const float* __restrict__ x, const int* __restrict__ adj,
    const float* __restrict__ uxp, const float* __restrict__ vxp,
    const float* __restrict__ cp, ushort_t* __restrict__ sout)
{
    const int wave = threadIdx.x >> 6;
    const int lane = threadIdx.x & 63;
    const int node = blockIdx.x * 4 + wave;      // grid is exactly BN/4
    const int b = node / NN;

    // ---- Phase A: lanes 0..15 own neighbor k = lane ----
    int jj = 0;
    if (lane < KK) jj = adj[(size_t)node*KK + lane];
    unsigned long long bal = __ballot(jj != 0);
    int deg = __popcll(bal);
    float inv = (deg > 0) ? (1.0f / (float)deg) : 0.0f;

    float q[MM];
    #pragma unroll
    for (int m = 0; m < MM; ++m) q[m] = 0.f;

    if (jj != 0) {
        const float* ur = uxp + (size_t)node * MM;               // wave-uniform
        const float* vr = vxp + ((size_t)b*NN + (jj - 1)) * MM;  // gathered
        float l[MM]; float mx = -1e30f;
        #pragma unroll
        for (int m = 0; m < MM; ++m) {
            l[m] = ur[m] + vr[m] + cp[m];
            mx = fmaxf(mx, l[m]);
        }
        float sum = 0.f;
        #pragma unroll
        for (int m = 0; m < MM; ++m) { l[m] = __expf(l[m] - mx); sum += l[m]; }
        float sc = inv / sum;   // fold inv_deg into q
        #pragma unroll
        for (int m = 0; m < MM; ++m) q[m] = l[m] * sc;
    }

    // ---- Phase B: s[m][c=lane] = sum_k q[k][m] * x[j_k][c] ----
    float s[MM];
    #pragma unroll
    for (int m = 0; m < MM; ++m) s[m] = 0.f;

    #pragma unroll
    for (int k = 0; k < KK; ++k) {
        int jjk = __builtin_amdgcn_readlane(jj, k);   // wave-uniform
        if (jjk != 0) {                               // uniform branch
            float xval = x[((size_t)b*NN + (jjk - 1)) * CC + lane];  // coalesced
            #pragma unroll
            for (int m = 0; m < MM; ++m) {
                float qkm = __uint_as_float(
                    __builtin_amdgcn_readlane(__float_as_uint(q[m]), k));
                s[m] = fmaf(qkm, xval, s[m]);
            }
        }
    }

    // store s as bf16, row-major [node][m*64 + c]: coalesced 2B stores per m
    ushort_t* so = sout + (size_t)node * MC + lane;
    #pragma unroll
    for (int m = 0; m < MM; ++m) so[m*CC] = f2bf(s[m]);
}

// ---------------------------------------------------------------------------
// Kernel 3: out[80000x64] = s[80000x576] @ wfb^T[576x64] + bias,
// bf16 MFMA 16x16x32. Block = 4 waves; wave w owns o-range [16w,16w+16);
// block owns 16 node rows. B-fragments (W) preloaded once (18 x 4 VGPRs).
// Layouts (m89/m120-verified): A: row=lane&15, k=(lane>>4)*8+j;
// B: col=lane&15, k=(lane>>4)*8+j; D: col=lane&15, row=(lane>>4)*4+reg.
// ---------------------------------------------------------------------------
__global__ __launch_bounds__(256) void stage2_kernel(
    const ushort_t* __restrict__ s, const ushort_t* __restrict__ wfb,
    const float* __restrict__ bias, float* __restrict__ out)
{
    const int wave = threadIdx.x >> 6;
    const int lane = threadIdx.x & 63;
    const int lr = lane & 15;
    const int lhi = lane >> 4;
    const int r0 = blockIdx.x * 16;
    const int o0 = wave * 16;

    bf16x8 bfrag[MC/32];
    #pragma unroll
    for (int ks = 0; ks < MC/32; ++ks)
        bfrag[ks] = *(const bf16x8*)(wfb + (size_t)(o0 + lr)*MC + ks*32 + lhi*8);

    f32x4 acc = {0.f, 0.f, 0.f, 0.f};
    const ushort_t* arow = s + (size_t)(r0 + lr) * MC + lhi*8;
    #pragma unroll
    for (int ks = 0; ks < MC/32; ++ks) {
        bf16x8 afrag = *(const bf16x8*)(arow + ks*32);
        acc = __builtin_amdgcn_mfma_f32_16x16x32_bf16(afrag, bfrag[ks], acc, 0, 0, 0);
    }

    float bv = bias[o0 + lr];
    #pragma unroll
    for (int reg = 0; reg < 4; ++reg) {
        int r = r0 + lhi*4 + reg;
        out[(size_t)r*OO + o0 + lr] = acc[reg] + bv;
    }
}

// ---------------------------------------------------------------------------
extern "C" void kernel_launch(void* const* d_in, const int* in_sizes, int n_in,
                              void* d_out, int out_size, void* d_ws, size_t ws_size,
                              hipStream_t stream)
{
    const float* x   = (const float*)d_in[0];
    const int*   adj = (const int*)  d_in[1];
    const float* W   = (const float*)d_in[2];
    const float* b   = (const float*)d_in[3];
    const float* u   = (const float*)d_in[4];
    const float* v   = (const float*)d_in[5];
    const float* c   = (const float*)d_in[6];
    float* out = (float*)d_out;

    // workspace layout (16B-aligned sections):
    //   ux  f32 [BN*9]            2,880,000 B
    //   vx  f32 [BN*9]            2,880,000 B
    //   wfb bf16 [64*576]            73,728 B
    //   s   bf16 [BN*576]        92,160,000 B   (total ~97.99 MB)
    float*    ux   = (float*)d_ws;
    float*    vx   = ux + (size_t)BN*MM;
    ushort_t* wfb  = (ushort_t*)(vx + (size_t)BN*MM);
    ushort_t* sbuf = wfb + (size_t)OO*MC;

    precompute_kernel<<<314, 256, 0, stream>>>(x, W, u, v, ux, vx, wfb);
    stage1_kernel<<<BN/4, 256, 0, stream>>>(x, adj, ux, vx, c, sbuf);
    stage2_kernel<<<BN/16, 256, 0, stream>>>(sbuf, wfb, b, out);
}

// Round 2
// 197.603 us; speedup vs baseline: 1.3649x; 1.3649x over previous
//
#include <hip/hip_runtime.h>
#include <cstdint>
#include <cstddef>

// Problem constants
#define BB 4
#define NN 20000
#define KK 16
#define MM 9
#define CC 64
#define OO 64
#define BN (BB*NN)       // 80000 nodes
#define MC (MM*CC)       // 576 flattened reduction dim
#define UVP 12           // padded ux/vx row (9 used + 3 pad) -> 48B, dwordx4-friendly
#define ROWP 584         // LDS s row pitch in bf16 elems (576+8): stride 1168B = 292 dw
                         // = 4 mod 32 banks -> fragment b128 reads hit the 8/bank floor

typedef __bf16 bf16x8 __attribute__((ext_vector_type(8)));
typedef float  f32x4  __attribute__((ext_vector_type(4)));
typedef unsigned short ushort_t;

__device__ __forceinline__ ushort_t f2bf(float f) {
    unsigned int u = __float_as_uint(f);
    u = (u + 0x7fffu + ((u >> 16) & 1u)) >> 16;   // RNE
    return (ushort_t)u;
}

// ---------------------------------------------------------------------------
// Precompute: uxc[n][m] = u[m]·x[n] + c[m], vxp[n][m] = v[m]·x[n]  (rows padded
// to 12 floats); plus W -> wfb[o][m*64+c] bf16 repack (B-operand layout).
// 64-thread blocks for even CU distribution: 1250 node blocks + 4 repack blocks.
// ---------------------------------------------------------------------------
__global__ __launch_bounds__(64) void precompute_kernel(
    const float* __restrict__ x, const float* __restrict__ W,
    const float* __restrict__ u, const float* __restrict__ v,
    const float* __restrict__ c,
    float* __restrict__ uxc, float* __restrict__ vxp, ushort_t* __restrict__ wfb)
{
    if (blockIdx.x >= 1250) {
        int base = (blockIdx.x - 1250) * 64 + threadIdx.x;
        for (int i = base; i < MM * OO * CC; i += 256) {
            int m = i >> 12;
            int rem = i & 4095;
            int o = rem >> 6;
            int cc = rem & 63;
            wfb[(size_t)o * MC + m * CC + cc] = f2bf(W[i]);
        }
        return;
    }
    int node = blockIdx.x * 64 + threadIdx.x;
    float au[MM], av[MM];
    #pragma unroll
    for (int m = 0; m < MM; ++m) { au[m] = 0.f; av[m] = 0.f; }
    const float4* xr = (const float4*)(x + (size_t)node * CC);
    #pragma unroll 4
    for (int c4 = 0; c4 < CC / 4; ++c4) {
        float4 xv = xr[c4];
        #pragma unroll
        for (int m = 0; m < MM; ++m) {
            const float* um = u + m * CC + c4 * 4;   // uniform -> scalar loads
            const float* vm = v + m * CC + c4 * 4;
            au[m] += um[0]*xv.x + um[1]*xv.y + um[2]*xv.z + um[3]*xv.w;
            av[m] += vm[0]*xv.x + vm[1]*xv.y + vm[2]*xv.z + vm[3]*xv.w;
        }
    }
    float cv[MM];
    #pragma unroll
    for (int m = 0; m < MM; ++m) cv[m] = c[m];
    float4* uo = (float4*)(uxc + (size_t)node * UVP);
    float4* vo = (float4*)(vxp + (size_t)node * UVP);
    uo[0] = make_float4(au[0]+cv[0], au[1]+cv[1], au[2]+cv[2], au[3]+cv[3]);
    uo[1] = make_float4(au[4]+cv[4], au[5]+cv[5], au[6]+cv[6], au[7]+cv[7]);
    uo[2] = make_float4(au[8]+cv[8], 0.f, 0.f, 0.f);
    vo[0] = make_float4(av[0], av[1], av[2], av[3]);
    vo[1] = make_float4(av[4], av[5], av[6], av[7]);
    vo[2] = make_float4(av[8], 0.f, 0.f, 0.f);
}

// ---------------------------------------------------------------------------
// Fused kernel: block = 4 waves = 16 nodes (one MFMA A-tile).
// Phase A: lane = (node-local g = lane>>4, neighbor k = lane&15); in-lane
//   softmax over M, inv_deg folded into q. All 64 lanes active.
// Phase B: per wave, 4 nodes x 16 k; q broadcast via v_readlane (VALU pipe);
//   s accumulated fp32, written bf16 to LDS in MFMA-A row layout.
// Phase C: each wave MFMAs the 16x576 s-tile against its 16-wide o-slice of W.
// Layouts (m89/m120-verified): A: row=lane&15, k=(lane>>4)*8+j;
// B: col=lane&15, k=(lane>>4)*8+j; D: col=lane&15, row=(lane>>4)*4+reg.
// ---------------------------------------------------------------------------
__global__ __launch_bounds__(256) void fused_kernel(
    const float* __restrict__ x, const int* __restrict__ adj,
    const float* __restrict__ uxc, const float* __restrict__ vxp,
    const ushort_t* __restrict__ wfb, const float* __restrict__ bias,
    float* __restrict__ out)
{
    __shared__ ushort_t slds[16 * ROWP];   // 18688 B
    const int tid = threadIdx.x;
    const int wave = tid >> 6;
    const int lane = tid & 63;
    const int node0 = blockIdx.x * 16;     // 16 | NN -> whole block in one batch
    const int b = node0 / NN;
    const float* xb = x + (size_t)b * NN * CC;

    // ---- Phase A: 4 nodes per wave in parallel across lane groups ----
    const int g = lane >> 4;               // node-local within wave
    const int node = node0 + wave * 4 + g;
    int jj = adj[(size_t)node0 * KK + tid];          // coalesced 256B/wave
    unsigned long long bal = __ballot(jj != 0);
    int deg = __popcll((bal >> (g * 16)) & 0xffffull);
    float inv = (deg > 0) ? (1.0f / (float)deg) : 0.0f;

    float q[MM];
    #pragma unroll
    for (int m = 0; m < MM; ++m) q[m] = 0.f;
    if (jj != 0) {
        const float4* ur = (const float4*)(uxc + (size_t)node * UVP);
        const float4* vr = (const float4*)(vxp + ((size_t)b * NN + (jj - 1)) * UVP);
        float4 u0 = ur[0], u1 = ur[1], u2 = ur[2];
        float4 v0 = vr[0], v1 = vr[1], v2 = vr[2];
        float l[MM] = { u0.x+v0.x, u0.y+v0.y, u0.z+v0.z, u0.w+v0.w,
                        u1.x+v1.x, u1.y+v1.y, u1.z+v1.z, u1.w+v1.w,
                        u2.x+v2.x };
        float mx = l[0];
        #pragma unroll
        for (int m = 1; m < MM; ++m) mx = fmaxf(mx, l[m]);
        float sum = 0.f;
        #pragma unroll
        for (int m = 0; m < MM; ++m) { l[m] = __expf(l[m] - mx); sum += l[m]; }
        float sc = inv / sum;
        #pragma unroll
        for (int m = 0; m < MM; ++m) q[m] = l[m] * sc;
    }

    // ---- Phase B: aggregate neighbors; s -> LDS (bf16) ----
    #pragma unroll
    for (int g2 = 0; g2 < 4; ++g2) {
        float s[MM];
        #pragma unroll
        for (int m = 0; m < MM; ++m) s[m] = 0.f;
        #pragma unroll
        for (int k = 0; k < KK; ++k) {
            int lsrc = g2 * 16 + k;
            int jjk = __builtin_amdgcn_readlane(jj, lsrc);    // SGPR
            int row = (jjk > 0) ? (jjk - 1) : 0;              // branchless; q=0 if pad
            float xv = xb[(size_t)row * CC + lane];           // coalesced 256B
            #pragma unroll
            for (int m = 0; m < MM; ++m) {
                float qk = __uint_as_float(
                    __builtin_amdgcn_readlane(__float_as_uint(q[m]), lsrc));
                s[m] = fmaf(qk, xv, s[m]);
            }
        }
        int r = wave * 4 + g2;
        #pragma unroll
        for (int m = 0; m < MM; ++m)
            slds[r * ROWP + m * CC + lane] = f2bf(s[m]);      // 32 dw/wave: no conflict
    }
    __syncthreads();

    // ---- Phase C: out[16 nodes][o-slice] = s @ W^T + bias ----
    const int lr = lane & 15, lhi = lane >> 4;
    const int o0 = wave * 16;
    f32x4 acc = {0.f, 0.f, 0.f, 0.f};
    #pragma unroll
    for (int ks = 0; ks < MC / 32; ++ks) {
        bf16x8 afrag = *(const bf16x8*)(slds + lr * ROWP + ks * 32 + lhi * 8);
        bf16x8 bfrag = *(const bf16x8*)(wfb + (size_t)(o0 + lr) * MC + ks * 32 + lhi * 8);
        acc = __builtin_amdgcn_mfma_f32_16x16x32_bf16(afrag, bfrag, acc, 0, 0, 0);
    }
    float bv = bias[o0 + lr];
    #pragma unroll
    for (int reg = 0; reg < 4; ++reg) {
        int rr = node0 + lhi * 4 + reg;
        out[(size_t)rr * OO + o0 + lr] = acc[reg] + bv;
    }
}

// ---------------------------------------------------------------------------
extern "C" void kernel_launch(void* const* d_in, const int* in_sizes, int n_in,
                              void* d_out, int out_size, void* d_ws, size_t ws_size,
                              hipStream_t stream)
{
    const float* x   = (const float*)d_in[0];
    const int*   adj = (const int*)  d_in[1];
    const float* W   = (const float*)d_in[2];
    const float* b   = (const float*)d_in[3];
    const float* u   = (const float*)d_in[4];
    const float* v   = (const float*)d_in[5];
    const float* c   = (const float*)d_in[6];
    float* out = (float*)d_out;

    // workspace: uxc f32 [80000*12] 3.84MB | vxp f32 [80000*12] 3.84MB
    //            wfb bf16 [64*576] 73.7KB   (total ~7.76 MB)
    float*    uxc = (float*)d_ws;
    float*    vxp = uxc + (size_t)BN * UVP;
    ushort_t* wfb = (ushort_t*)(vxp + (size_t)BN * UVP);

    precompute_kernel<<<1254, 64, 0, stream>>>(x, W, u, v, c, uxc, vxp, wfb);
    fused_kernel<<<BN / 16, 256, 0, stream>>>(x, adj, uxc, vxp, wfb, b, out);
}

// Round 3
// 173.874 us; speedup vs baseline: 1.5512x; 1.1365x over previous
//
#include <hip/hip_runtime.h>
#include <cstdint>
#include <cstddef>

// Problem constants
#define BB 4
#define NN 20000
#define KK 16
#define MM 9
#define CC 64
#define OO 64
#define BN (BB*NN)       // 80000 nodes
#define MC (MM*CC)       // 576 flattened reduction dim
#define UVP 12           // padded ux/vx row (9 used + 3 pad), float4-friendly
#define ROWP 584         // slds row pitch in bf16 elems (576+8)
#define QP  272          // qlds node stride in bf16 elems = 17*16 (pad m-dim:
                         // write banks g*8+k/2 -> conflict-free; b128 16B-aligned)

typedef __bf16 bf16x8 __attribute__((ext_vector_type(8)));
typedef float  f32x4  __attribute__((ext_vector_type(4)));
typedef unsigned short ushort_t;
typedef unsigned int   uint_t;

__device__ __forceinline__ ushort_t f2bf(float f) {
    uint_t u = __float_as_uint(f);
    u = (u + 0x7fffu + ((u >> 16) & 1u)) >> 16;   // RNE
    return (ushort_t)u;
}
__device__ __forceinline__ float bf2f(ushort_t h) {
    return __uint_as_float((uint_t)h << 16);
}

// ---------------------------------------------------------------------------
// Setup: x -> xh/xl bf16 split; W -> wfb[o][m*64+c] bf16; (u,v) -> G[32][64]
// hi/lo bf16 (rows 0..8 = u, 9..17 = v, 18..31 = 0), B-operand layout.
// ---------------------------------------------------------------------------
__global__ __launch_bounds__(256) void setup_kernel(
    const float* __restrict__ x, const float* __restrict__ W,
    const float* __restrict__ u, const float* __restrict__ v,
    ushort_t* __restrict__ xh, ushort_t* __restrict__ xl,
    ushort_t* __restrict__ wfb, ushort_t* __restrict__ Gh, ushort_t* __restrict__ Gl)
{
    int bid = blockIdx.x;
    if (bid < 5000) {                       // x split: 5000*1024 = 5.12M elems
        int i = bid * 1024 + threadIdx.x * 4;
        float4 xv = *(const float4*)(x + i);
        ushort_t h0 = f2bf(xv.x), h1 = f2bf(xv.y), h2 = f2bf(xv.z), h3 = f2bf(xv.w);
        ushort4 hv; hv.x = h0; hv.y = h1; hv.z = h2; hv.w = h3;
        *(ushort4*)(xh + i) = hv;
        ushort4 lv;
        lv.x = f2bf(xv.x - bf2f(h0)); lv.y = f2bf(xv.y - bf2f(h1));
        lv.z = f2bf(xv.z - bf2f(h2)); lv.w = f2bf(xv.w - bf2f(h3));
        *(ushort4*)(xl + i) = lv;
    } else if (bid < 5144) {                // W repack: 144*256 = 36864 elems
        int i = (bid - 5000) * 256 + threadIdx.x;
        int m = i >> 12, rem = i & 4095, o = rem >> 6, cc = rem & 63;
        wfb[(size_t)o * MC + m * CC + cc] = f2bf(W[i]);
    } else {                                // G build: 8*256 = 2048 elems
        int i = (bid - 5144) * 256 + threadIdx.x;
        int r = i >> 6, k = i & 63;
        float val = (r < 9) ? u[r * 64 + k] : ((r < 18) ? v[(r - 9) * 64 + k] : 0.f);
        ushort_t h = f2bf(val);
        Gh[i] = h;
        Gl[i] = f2bf(val - bf2f(h));
    }
}

// ---------------------------------------------------------------------------
// uxvx GEMM: [80000x64] @ G^T[64x32] -> uxc (cols 0..8, +c) / vxp (cols 9..17).
// bf16 hi/lo split (xh*Gh + xh*Gl + xl*Gh) keeps logits fp32-accurate.
// Wave = 16 nodes; 2 k-steps x 2 col-tiles x 3 split passes = 12 MFMAs.
// Layouts (verified): A row=lane&15, k=(lane>>4)*8+j; B col=lane&15, same k;
// D col=lane&15, row=(lane>>4)*4+reg.
// ---------------------------------------------------------------------------
__global__ __launch_bounds__(256) void uxvx_kernel(
    const ushort_t* __restrict__ xh, const ushort_t* __restrict__ xl,
    const ushort_t* __restrict__ Gh, const ushort_t* __restrict__ Gl,
    const float* __restrict__ c, float* __restrict__ uxc, float* __restrict__ vxp)
{
    const int wave = threadIdx.x >> 6, lane = threadIdx.x & 63;
    const int lr = lane & 15, lhi = lane >> 4;
    const int t0 = blockIdx.x * 64 + wave * 16;

    const ushort_t* xrh = xh + (size_t)(t0 + lr) * 64 + lhi * 8;
    const ushort_t* xrl = xl + (size_t)(t0 + lr) * 64 + lhi * 8;
    bf16x8 ah0 = *(const bf16x8*)(xrh),      ah1 = *(const bf16x8*)(xrh + 32);
    bf16x8 al0 = *(const bf16x8*)(xrl),      al1 = *(const bf16x8*)(xrl + 32);

    f32x4 acc0 = {0.f,0.f,0.f,0.f}, acc1 = {0.f,0.f,0.f,0.f};
    #pragma unroll
    for (int t = 0; t < 2; ++t) {
        f32x4 acc = {0.f,0.f,0.f,0.f};
        #pragma unroll
        for (int s = 0; s < 2; ++s) {
            const ushort_t* gp = Gh + (t * 16 + lr) * 64 + s * 32 + lhi * 8;
            const ushort_t* lp = Gl + (t * 16 + lr) * 64 + s * 32 + lhi * 8;
            bf16x8 gh = *(const bf16x8*)gp;
            bf16x8 gl = *(const bf16x8*)lp;
            bf16x8 as = s ? ah1 : ah0;
            bf16x8 asl = s ? al1 : al0;
            acc = __builtin_amdgcn_mfma_f32_16x16x32_bf16(as,  gh, acc, 0, 0, 0);
            acc = __builtin_amdgcn_mfma_f32_16x16x32_bf16(as,  gl, acc, 0, 0, 0);
            acc = __builtin_amdgcn_mfma_f32_16x16x32_bf16(asl, gh, acc, 0, 0, 0);
        }
        if (t == 0) acc0 = acc; else acc1 = acc;
    }

    float cv = (lr < 9) ? c[lr] : 0.f;
    #pragma unroll
    for (int reg = 0; reg < 4; ++reg) {
        int node = t0 + lhi * 4 + reg;
        if (lr < 9) uxc[(size_t)node * UVP + lr] = acc0[reg] + cv;
        else        vxp[(size_t)node * UVP + (lr - 9)] = acc0[reg];
        if (lr < 2) vxp[(size_t)node * UVP + 7 + lr] = acc1[reg];
    }
}

// ---------------------------------------------------------------------------
// Fused: block = 4 waves = 16 nodes.
// Phase A: lane=(g,k); softmax over M; inv_deg folded into q; q -> qlds bf16
//          in A-operand layout [node][m][k] (k contiguous).
// Phase B (MFMA): per node, s[m][c] = Q[16x16(pad)] @ Xg[16x64]; one
//          16x16x32 MFMA per 16-col chunk, upper k-half zeroed via A-frag
//          (B garbage there multiplies 0). Gather rows via ds_bpermute of the
//          wave-resident adj; same 8 voffsets reused across c-chunks via imm
//          offsets. x gathered as bf16 (xh). D (m<9) -> slds bf16.
// Phase C: 16x576 @ 576x64 MFMA + bias (unchanged, verified).
// ---------------------------------------------------------------------------
__global__ __launch_bounds__(256) void fused_kernel(
    const ushort_t* __restrict__ xh, const int* __restrict__ adj,
    const float* __restrict__ uxc, const float* __restrict__ vxp,
    const ushort_t* __restrict__ wfb, const float* __restrict__ bias,
    float* __restrict__ out)
{
    __shared__ ushort_t qlds[16 * QP];     //  8704 B
    __shared__ ushort_t slds[16 * ROWP];   // 18688 B
    const int tid = threadIdx.x, wave = tid >> 6, lane = tid & 63;
    const int lr = lane & 15, lhi = lane >> 4;
    const int node0 = blockIdx.x * 16;
    const int b = node0 / NN;
    const int rowbase = b * NN;

    // ---- Phase A ----
    const int g = lhi;                       // node-local within wave
    const int k = lr;                        // neighbor index
    const int node = node0 + wave * 4 + g;
    int jj = adj[(size_t)node0 * KK + tid];  // coalesced; lane (g,k) owns edge
    unsigned long long bal = __ballot(jj != 0);
    int deg = __popcll((bal >> (g * 16)) & 0xffffull);
    float inv = (deg > 0) ? (1.0f / (float)deg) : 0.0f;

    float q[MM];
    #pragma unroll
    for (int m = 0; m < MM; ++m) q[m] = 0.f;
    if (jj != 0) {
        const float4* ur = (const float4*)(uxc + (size_t)node * UVP);
        const float4* vr = (const float4*)(vxp + ((size_t)rowbase + (jj - 1)) * UVP);
        float4 u0 = ur[0], u1 = ur[1], u2 = ur[2];
        float4 v0 = vr[0], v1 = vr[1], v2 = vr[2];
        float l[MM] = { u0.x+v0.x, u0.y+v0.y, u0.z+v0.z, u0.w+v0.w,
                        u1.x+v1.x, u1.y+v1.y, u1.z+v1.z, u1.w+v1.w,
                        u2.x+v2.x };
        float mx = l[0];
        #pragma unroll
        for (int m = 1; m < MM; ++m) mx = fmaxf(mx, l[m]);
        float sum = 0.f;
        #pragma unroll
        for (int m = 0; m < MM; ++m) { l[m] = __expf(l[m] - mx); sum += l[m]; }
        float sc = inv / sum;
        #pragma unroll
        for (int m = 0; m < MM; ++m) q[m] = l[m] * sc;
    }
    // q -> qlds (bf16), layout [node][m][k]; same-wave consumer, no barrier
    {
        ushort_t* qw = qlds + (wave * 4 + g) * QP + k;
        #pragma unroll
        for (int m = 0; m < MM; ++m) qw[m * 16] = f2bf(q[m]);
    }

    // ---- Phase B: per-node MFMA aggregation ----
    const int idxbase = (lane & 16) * 2;     // (khi&1)*32 bytes for bpermute idx
    const int sbase = rowbase - 1;
    #pragma unroll 1
    for (int g2 = 0; g2 < 4; ++g2) {
        const int rnode = wave * 4 + g2;
        // per-lane gather row offsets (elems) via bpermute of adj lanes
        uint_t voffe[8];
        #pragma unroll
        for (int j = 0; j < 8; ++j) {
            int jp = __builtin_amdgcn_ds_bpermute(g2 * 64 + j * 4 + idxbase, jj);
            int row = ((jp < 1) ? 1 : jp) + sbase;       // pad -> rowbase (q=0)
            voffe[j] = (uint_t)row * 64 + (uint_t)lr;    // elem index
        }
        // 32 ushort gathers: 8 voffsets x 4 imm c-chunk offsets
        ushort_t val[4][8];
        #pragma unroll
        for (int j = 0; j < 8; ++j) {
            const ushort_t* pj = xh + voffe[j];
            #pragma unroll
            for (int cc = 0; cc < 4; ++cc) val[cc][j] = pj[cc * 16];
        }
        // A-frag: q rows (zero for k>=16 half)
        bf16x8 qfrag = {};
        if (lhi < 2)
            qfrag = *(const bf16x8*)(qlds + rnode * QP + lr * 16 + lhi * 8);
        #pragma unroll
        for (int cc = 0; cc < 4; ++cc) {
            union { uint_t u[4]; bf16x8 v; } bf;
            bf.u[0] = __builtin_amdgcn_perm((uint_t)val[cc][1], (uint_t)val[cc][0], 0x05040100u);
            bf.u[1] = __builtin_amdgcn_perm((uint_t)val[cc][3], (uint_t)val[cc][2], 0x05040100u);
            bf.u[2] = __builtin_amdgcn_perm((uint_t)val[cc][5], (uint_t)val[cc][4], 0x05040100u);
            bf.u[3] = __builtin_amdgcn_perm((uint_t)val[cc][7], (uint_t)val[cc][6], 0x05040100u);
            f32x4 accB = {0.f,0.f,0.f,0.f};
            accB = __builtin_amdgcn_mfma_f32_16x16x32_bf16(qfrag, bf.v, accB, 0, 0, 0);
            #pragma unroll
            for (int reg = 0; reg < 4; ++reg) {
                int m = lhi * 4 + reg;
                if (m < 9)
                    slds[rnode * ROWP + m * CC + cc * 16 + lr] = f2bf(accB[reg]);
            }
        }
    }
    __syncthreads();

    // ---- Phase C: out[16 nodes][o-slice] = s @ W^T + bias ----
    const int o0 = wave * 16;
    f32x4 acc = {0.f,0.f,0.f,0.f};
    #pragma unroll
    for (int ks = 0; ks < MC / 32; ++ks) {
        bf16x8 afrag = *(const bf16x8*)(slds + lr * ROWP + ks * 32 + lhi * 8);
        bf16x8 bfrag = *(const bf16x8*)(wfb + (size_t)(o0 + lr) * MC + ks * 32 + lhi * 8);
        acc = __builtin_amdgcn_mfma_f32_16x16x32_bf16(afrag, bfrag, acc, 0, 0, 0);
    }
    float bv = bias[o0 + lr];
    #pragma unroll
    for (int reg = 0; reg < 4; ++reg) {
        int rr = node0 + lhi * 4 + reg;
        out[(size_t)rr * OO + o0 + lr] = acc[reg] + bv;
    }
}

// ---------------------------------------------------------------------------
extern "C" void kernel_launch(void* const* d_in, const int* in_sizes, int n_in,
                              void* d_out, int out_size, void* d_ws, size_t ws_size,
                              hipStream_t stream)
{
    const float* x   = (const float*)d_in[0];
    const int*   adj = (const int*)  d_in[1];
    const float* W   = (const float*)d_in[2];
    const float* b   = (const float*)d_in[3];
    const float* u   = (const float*)d_in[4];
    const float* v   = (const float*)d_in[5];
    const float* c   = (const float*)d_in[6];
    float* out = (float*)d_out;

    // workspace layout (all sections 16B-aligned):
    //   uxc f32 [BN*12]   3.84 MB
    //   vxp f32 [BN*12]   3.84 MB
    //   xh  bf16 [BN*64] 10.24 MB
    //   xl  bf16 [BN*64] 10.24 MB
    //   wfb bf16 [36864]  73.7 KB
    //   Gh  bf16 [2048]    4 KB
    //   Gl  bf16 [2048]    4 KB     total ~28.3 MB
    float*    uxc = (float*)d_ws;
    float*    vxp = uxc + (size_t)BN * UVP;
    ushort_t* xh  = (ushort_t*)(vxp + (size_t)BN * UVP);
    ushort_t* xl  = xh + (size_t)BN * CC;
    ushort_t* wfb = xl + (size_t)BN * CC;
    ushort_t* Gh  = wfb + (size_t)MM * OO * CC;
    ushort_t* Gl  = Gh + 2048;

    setup_kernel<<<5152, 256, 0, stream>>>(x, W, u, v, xh, xl, wfb, Gh, Gl);
    uxvx_kernel<<<1250, 256, 0, stream>>>(xh, xl, Gh, Gl, c, uxc, vxp);
    fused_kernel<<<5000, 256, 0, stream>>>(xh, adj, uxc, vxp, wfb, b, out);
}

// Round 4
// 158.498 us; speedup vs baseline: 1.7016x; 1.0970x over previous
//
#include <hip/hip_runtime.h>
#include <cstdint>
#include <cstddef>

// Problem constants
#define BB 4
#define NN 20000
#define KK 16
#define MM 9
#define CC 64
#define OO 64
#define BN (BB*NN)       // 80000 nodes
#define MC (MM*CC)       // 576 flattened reduction dim
#define UVP 12           // padded ux/vx row (9 used + 3 pad) fp32
#define QNP 272          // qlds node pitch (u16): 16 m-rows x 16 k + 16 pad
                         // (272*2/4 = 136 dwords ≡ 8 mod 32 -> node writes spread banks)
#define SCP 72           // slds c-pitch per m-row (u16): 144B breaks 128B bank collapse
#define SNP (MM*SCP)     // 648 u16 per node
#define NKS (MC/32)      // 18 K-steps in Phase C

typedef _Float16 f16x8 __attribute__((ext_vector_type(8)));
typedef float    f32x4 __attribute__((ext_vector_type(4)));
typedef unsigned short u16;
typedef unsigned int   u32;

union Hcv { _Float16 h; u16 u; };
__device__ __forceinline__ u16 f2h(float f) { Hcv t; t.h = (_Float16)f; return t.u; }
__device__ __forceinline__ float h2f(u16 h) { Hcv t; t.u = h; return (float)t.h; }

// ---------------------------------------------------------------------------
// Setup: x -> xh/xl f16 split; W -> wfb2 f16 in fragment order [ks][lhi][o][8j]
// (Phase C B-frag loads become 4 dense 256B runs); (u,v) -> G[32][64] f16 hi/lo.
// ---------------------------------------------------------------------------
__global__ __launch_bounds__(256) void setup_kernel(
    const float* __restrict__ x, const float* __restrict__ W,
    const float* __restrict__ u, const float* __restrict__ v,
    u16* __restrict__ xh, u16* __restrict__ xl,
    u16* __restrict__ wfb2, u16* __restrict__ Gh, u16* __restrict__ Gl)
{
    int bid = blockIdx.x;
    if (bid < 5000) {                        // x split: 5000*1024 = 5.12M elems
        int i = bid * 1024 + threadIdx.x * 4;
        float4 xv = *(const float4*)(x + i);
        u16 h0 = f2h(xv.x), h1 = f2h(xv.y), h2 = f2h(xv.z), h3 = f2h(xv.w);
        ushort4 hv; hv.x = h0; hv.y = h1; hv.z = h2; hv.w = h3;
        *(ushort4*)(xh + i) = hv;
        ushort4 lv;
        lv.x = f2h(xv.x - h2f(h0)); lv.y = f2h(xv.y - h2f(h1));
        lv.z = f2h(xv.z - h2f(h2)); lv.w = f2h(xv.w - h2f(h3));
        *(ushort4*)(xl + i) = lv;
    } else if (bid < 5144) {                 // W swizzle: 144*256 = 36864 elems
        int i = (bid - 5000) * 256 + threadIdx.x;
        int j = i & 7, o = (i >> 3) & 63, lhi = (i >> 9) & 3, ks = i >> 11;
        int kf = ks * 32 + lhi * 8 + j;
        int m = kf >> 6, cc = kf & 63;
        wfb2[i] = f2h(W[m * 4096 + o * 64 + cc]);
    } else {                                 // G build: 8*256 = 2048 elems
        int i = (bid - 5144) * 256 + threadIdx.x;
        int r = i >> 6, cc = i & 63;
        float val = (r < 9) ? u[r * 64 + cc] : ((r < 18) ? v[(r - 9) * 64 + cc] : 0.f);
        u16 h = f2h(val);
        Gh[i] = h;
        Gl[i] = f2h(val - h2f(h));
    }
}

// ---------------------------------------------------------------------------
// uxvx GEMM: [80000x64] @ G^T[64x32] -> uxc (cols 0..8, +c) / vxp (cols 9..17).
// f16 hi/lo split (xh*Gh + xh*Gl + xl*Gh) keeps logits fp32-accurate.
// ---------------------------------------------------------------------------
__global__ __launch_bounds__(256) void uxvx_kernel(
    const u16* __restrict__ xh, const u16* __restrict__ xl,
    const u16* __restrict__ Gh, const u16* __restrict__ Gl,
    const float* __restrict__ c, float* __restrict__ uxc, float* __restrict__ vxp)
{
    const int wave = threadIdx.x >> 6, lane = threadIdx.x & 63;
    const int lr = lane & 15, lhi = lane >> 4;
    const int t0 = blockIdx.x * 64 + wave * 16;

    const u16* xrh = xh + (size_t)(t0 + lr) * 64 + lhi * 8;
    const u16* xrl = xl + (size_t)(t0 + lr) * 64 + lhi * 8;
    f16x8 ah0 = *(const f16x8*)(xrh), ah1 = *(const f16x8*)(xrh + 32);
    f16x8 al0 = *(const f16x8*)(xrl), al1 = *(const f16x8*)(xrl + 32);

    f32x4 acc0 = {0.f,0.f,0.f,0.f}, acc1 = {0.f,0.f,0.f,0.f};
    #pragma unroll
    for (int t = 0; t < 2; ++t) {
        f32x4 acc = {0.f,0.f,0.f,0.f};
        #pragma unroll
        for (int s = 0; s < 2; ++s) {
            f16x8 gh = *(const f16x8*)(Gh + (t * 16 + lr) * 64 + s * 32 + lhi * 8);
            f16x8 gl = *(const f16x8*)(Gl + (t * 16 + lr) * 64 + s * 32 + lhi * 8);
            f16x8 as  = s ? ah1 : ah0;
            f16x8 asl = s ? al1 : al0;
            acc = __builtin_amdgcn_mfma_f32_16x16x32_f16(as,  gh, acc, 0, 0, 0);
            acc = __builtin_amdgcn_mfma_f32_16x16x32_f16(as,  gl, acc, 0, 0, 0);
            acc = __builtin_amdgcn_mfma_f32_16x16x32_f16(asl, gh, acc, 0, 0, 0);
        }
        if (t == 0) acc0 = acc; else acc1 = acc;
    }

    float cv = (lr < 9) ? c[lr] : 0.f;
    #pragma unroll
    for (int reg = 0; reg < 4; ++reg) {
        int node = t0 + lhi * 4 + reg;
        if (lr < 9) uxc[(size_t)node * UVP + lr] = acc0[reg] + cv;
        else        vxp[(size_t)node * UVP + (lr - 9)] = acc0[reg];
        if (lr < 2) vxp[(size_t)node * UVP + 7 + lr] = acc1[reg];
    }
}

// ---------------------------------------------------------------------------
// Fused: block = 4 waves = 16 nodes.
// Phase A: lane=(g,k); softmax over M; inv_deg folded into q; q -> qlds f16
//          layout [node][m][k] (k contiguous; m 9..15 + pad pre-zeroed).
// Phase B: D[c][m] = Xg^T @ Q per node. A-frag = gathered x: per load instr
//          the row is uniform per 16-lane group (2 dense 32B segments -> cheap
//          TA). Lanes k>=16 hold zero A. B-frag = 1 ds_read_b128 of q, reused
//          across 4 c-chunks. D rows = 4 consecutive c -> packed ds_write_b64
//          into slds [node][m][c] (c-pitch 72 breaks bank collapse).
// Phase C: out[16x64] = s[16x576] @ W'[576x64] + bias via f16 MFMA; W' in
//          fragment-order layout (dense 256B runs).
// Layouts (m89/m101/m121-128 verified, dtype-independent):
//   A row=lane&15, k=(lane>>4)*8+j; B col=lane&15, same k;
//   D col=lane&15, row=(lane>>4)*4+reg.
// ---------------------------------------------------------------------------
__global__ __launch_bounds__(256) void fused_kernel(
    const u16* __restrict__ xh, const int* __restrict__ adj,
    const float* __restrict__ uxc, const float* __restrict__ vxp,
    const u16* __restrict__ wfb2, const float* __restrict__ bias,
    float* __restrict__ out)
{
    __shared__ __align__(16) u16 qlds[16 * QNP];   //  8704 B
    __shared__ __align__(16) u16 slds[16 * SNP];   // 20736 B
    const int tid = threadIdx.x, wave = tid >> 6, lane = tid & 63;
    const int lr = lane & 15, lhi = lane >> 4;
    const int node0 = blockIdx.x * 16;
    const int b = node0 / NN;
    const int rowbase = b * NN;

    // zero qlds (covers m 9..15 rows, k-spill pad; avoids NaN into real cols)
    {
        uint4* qz = (uint4*)qlds;
        #pragma unroll
        for (int i = tid; i < 16 * QNP / 8; i += 256) qz[i] = make_uint4(0,0,0,0);
    }
    __syncthreads();

    // ---- Phase A ----
    const int g = lhi;                        // node-local within wave
    const int k = lr;                         // neighbor index
    const int node = node0 + wave * 4 + g;
    int jj = adj[(size_t)node0 * KK + tid];   // coalesced; lane (g,k) owns edge
    unsigned long long bal = __ballot(jj != 0);
    int deg = __popcll((bal >> (g * 16)) & 0xffffull);
    float inv = (deg > 0) ? (1.0f / (float)deg) : 0.0f;

    float q[MM];
    #pragma unroll
    for (int m = 0; m < MM; ++m) q[m] = 0.f;
    if (jj != 0) {
        const float4* ur = (const float4*)(uxc + (size_t)node * UVP);
        const float4* vr = (const float4*)(vxp + ((size_t)rowbase + (jj - 1)) * UVP);
        float4 u0 = ur[0], u1 = ur[1], u2 = ur[2];
        float4 v0 = vr[0], v1 = vr[1], v2 = vr[2];
        float l[MM] = { u0.x+v0.x, u0.y+v0.y, u0.z+v0.z, u0.w+v0.w,
                        u1.x+v1.x, u1.y+v1.y, u1.z+v1.z, u1.w+v1.w,
                        u2.x+v2.x };
        float mx = l[0];
        #pragma unroll
        for (int m = 1; m < MM; ++m) mx = fmaxf(mx, l[m]);
        float sum = 0.f;
        #pragma unroll
        for (int m = 0; m < MM; ++m) { l[m] = __expf(l[m] - mx); sum += l[m]; }
        float sc = inv / sum;
        #pragma unroll
        for (int m = 0; m < MM; ++m) q[m] = l[m] * sc;
    }
    {   // q -> qlds [node][m*16 + k]; same-wave consumer, no barrier needed
        u16* qw = qlds + (wave * 4 + g) * QNP + k;
        #pragma unroll
        for (int m = 0; m < MM; ++m) qw[m * 16] = f2h(q[m]);
    }

    // ---- Phase B: per-node MFMA aggregation, D[c][m] = Xg^T @ Q ----
    const u16* xhb = xh + ((size_t)rowbase << 6);
    #pragma unroll 1
    for (int g2 = 0; g2 < 4; ++g2) {
        const int rnode = wave * 4 + g2;
        // edge rows (uniform per 16-lane group): lhi=0 -> k=j, lhi=1 -> k=8+j
        int erow[8];
        #pragma unroll
        for (int j = 0; j < 8; ++j) {
            int e0 = __builtin_amdgcn_readlane(jj, g2 * 16 + j);
            int e1 = __builtin_amdgcn_readlane(jj, g2 * 16 + 8 + j);
            int e = (lane & 16) ? e1 : e0;
            erow[j] = (e > 0) ? (e - 1) : 0;      // pad -> row 0 (q=0 kills it)
        }
        f16x8 bfragQ = *(const f16x8*)(qlds + rnode * QNP + lr * 16 + lhi * 8);
        #pragma unroll
        for (int cc = 0; cc < 4; ++cc) {
            u16 vals[8];
            if (lane < 32) {
                #pragma unroll
                for (int j = 0; j < 8; ++j)
                    vals[j] = xhb[(size_t)erow[j] * 64 + cc * 16 + lr];
            } else {
                #pragma unroll
                for (int j = 0; j < 8; ++j) vals[j] = 0;   // k>=16 -> A=0
            }
            union { u32 u[4]; f16x8 v; } af;
            af.u[0] = __builtin_amdgcn_perm((u32)vals[1], (u32)vals[0], 0x05040100u);
            af.u[1] = __builtin_amdgcn_perm((u32)vals[3], (u32)vals[2], 0x05040100u);
            af.u[2] = __builtin_amdgcn_perm((u32)vals[5], (u32)vals[4], 0x05040100u);
            af.u[3] = __builtin_amdgcn_perm((u32)vals[7], (u32)vals[6], 0x05040100u);
            f32x4 accB = {0.f,0.f,0.f,0.f};
            accB = __builtin_amdgcn_mfma_f32_16x16x32_f16(af.v, bfragQ, accB, 0, 0, 0);
            if (lr < 9) {   // lane col = m = lr; rows = c = cc*16 + lhi*4 + reg
                u32 lo = __builtin_amdgcn_perm((u32)f2h(accB[1]), (u32)f2h(accB[0]), 0x05040100u);
                u32 hi = __builtin_amdgcn_perm((u32)f2h(accB[3]), (u32)f2h(accB[2]), 0x05040100u);
                uint2* p = (uint2*)(slds + rnode * SNP + lr * SCP + cc * 16 + lhi * 4);
                *p = make_uint2(lo, hi);
            }
        }
    }
    __syncthreads();

    // ---- Phase C: out[16 nodes][o-slice] = s @ W' + bias ----
    const int o0 = wave * 16;
    f32x4 acc = {0.f,0.f,0.f,0.f};
    #pragma unroll
    for (int ks = 0; ks < NKS; ++ks) {
        int kf = ks * 32 + lhi * 8;
        int m = kf >> 6, coff = kf & 63;
        f16x8 afrag = *(const f16x8*)(slds + lr * SNP + m * SCP + coff);
        f16x8 bfrag = *(const f16x8*)(wfb2 + (size_t)(((ks * 4 + lhi) * 64) + o0 + lr) * 8);
        acc = __builtin_amdgcn_mfma_f32_16x16x32_f16(afrag, bfrag, acc, 0, 0, 0);
    }
    float bv = bias[o0 + lr];
    #pragma unroll
    for (int reg = 0; reg < 4; ++reg) {
        int rr = node0 + lhi * 4 + reg;
        out[(size_t)rr * OO + o0 + lr] = acc[reg] + bv;
    }
}

// ---------------------------------------------------------------------------
extern "C" void kernel_launch(void* const* d_in, const int* in_sizes, int n_in,
                              void* d_out, int out_size, void* d_ws, size_t ws_size,
                              hipStream_t stream)
{
    const float* x   = (const float*)d_in[0];
    const int*   adj = (const int*)  d_in[1];
    const float* W   = (const float*)d_in[2];
    const float* b   = (const float*)d_in[3];
    const float* u   = (const float*)d_in[4];
    const float* v   = (const float*)d_in[5];
    const float* c   = (const float*)d_in[6];
    float* out = (float*)d_out;

    // workspace layout (16B-aligned sections):
    //   uxc  f32 [BN*12]   3.84 MB
    //   vxp  f32 [BN*12]   3.84 MB
    //   xh   f16 [BN*64]  10.24 MB
    //   xl   f16 [BN*64]  10.24 MB
    //   wfb2 f16 [36864]   73.7 KB
    //   Gh/Gl f16 [2048]    4 KB each      total ~28.3 MB
    float* uxc = (float*)d_ws;
    float* vxp = uxc + (size_t)BN * UVP;
    u16*   xh  = (u16*)(vxp + (size_t)BN * UVP);
    u16*   xl  = xh + (size_t)BN * CC;
    u16*   wfb2= xl + (size_t)BN * CC;
    u16*   Gh  = wfb2 + (size_t)NKS * 2048;
    u16*   Gl  = Gh + 2048;

    setup_kernel<<<5152, 256, 0, stream>>>(x, W, u, v, xh, xl, wfb2, Gh, Gl);
    uxvx_kernel<<<1250, 256, 0, stream>>>(xh, xl, Gh, Gl, c, uxc, vxp);
    fused_kernel<<<5000, 256, 0, stream>>>(xh, adj, uxc, vxp, wfb2, b, out);
}

// Round 6
// 140.614 us; speedup vs baseline: 1.9181x; 1.1272x over previous
//
#include <hip/hip_runtime.h>
#include <cstdint>
#include <cstddef>

// Problem constants
#define BB 4
#define NN 20000
#define KK 16
#define MM 9
#define CC 64
#define OO 64
#define BN (BB*NN)       // 80000 nodes
#define MC (MM*CC)       // 576 flattened reduction dim
#define UVP 12           // padded ux/vx row (9 used + 3 pad) fp32
#define QNP 272          // qlds node pitch (u16): 16 m x 16 k + 16 pad (bank spread)
#define SCP 72           // slds c-pitch per m-row (u16): 144B breaks 128B bank collapse
#define SNP (MM*SCP)     // 648 u16 per node
#define NKS (MC/32)      // 18 K-steps in Phase C

typedef _Float16 f16x8 __attribute__((ext_vector_type(8)));
typedef _Float16 f16x4 __attribute__((ext_vector_type(4)));
typedef __fp16   fp16v2 __attribute__((ext_vector_type(2)));   // pkrtz return type
typedef float    f32x4 __attribute__((ext_vector_type(4)));
typedef unsigned short u16;
typedef unsigned int   u32;

union Hcv { _Float16 h; u16 u; };
__device__ __forceinline__ u16 f2h(float f) { Hcv t; t.h = (_Float16)f; return t.u; }
__device__ __forceinline__ float h2f(u16 h) { Hcv t; t.u = h; return (float)t.h; }

// ---------------------------------------------------------------------------
// Setup: x -> xh/xl f16 split; W -> wfb2 f16 in fragment order [ks][lhi][o][8j];
// (u,v) -> G[32][64] f16 hi/lo.
// ---------------------------------------------------------------------------
__global__ __launch_bounds__(256) void setup_kernel(
    const float* __restrict__ x, const float* __restrict__ W,
    const float* __restrict__ u, const float* __restrict__ v,
    u16* __restrict__ xh, u16* __restrict__ xl,
    u16* __restrict__ wfb2, u16* __restrict__ Gh, u16* __restrict__ Gl)
{
    int bid = blockIdx.x;
    if (bid < 5000) {                        // x split: 5000*1024 = 5.12M elems
        int i = bid * 1024 + threadIdx.x * 4;
        float4 xv = *(const float4*)(x + i);
        u16 h0 = f2h(xv.x), h1 = f2h(xv.y), h2 = f2h(xv.z), h3 = f2h(xv.w);
        ushort4 hv; hv.x = h0; hv.y = h1; hv.z = h2; hv.w = h3;
        *(ushort4*)(xh + i) = hv;
        ushort4 lv;
        lv.x = f2h(xv.x - h2f(h0)); lv.y = f2h(xv.y - h2f(h1));
        lv.z = f2h(xv.z - h2f(h2)); lv.w = f2h(xv.w - h2f(h3));
        *(ushort4*)(xl + i) = lv;
    } else if (bid < 5144) {                 // W swizzle: 144*256 = 36864 elems
        int i = (bid - 5000) * 256 + threadIdx.x;
        int j = i & 7, o = (i >> 3) & 63, lhi = (i >> 9) & 3, ks = i >> 11;
        int kf = ks * 32 + lhi * 8 + j;
        int m = kf >> 6, cc = kf & 63;
        wfb2[i] = f2h(W[m * 4096 + o * 64 + cc]);
    } else {                                 // G build: 8*256 = 2048 elems
        int i = (bid - 5144) * 256 + threadIdx.x;
        int r = i >> 6, cc = i & 63;
        float val = (r < 9) ? u[r * 64 + cc] : ((r < 18) ? v[(r - 9) * 64 + cc] : 0.f);
        u16 h = f2h(val);
        Gh[i] = h;
        Gl[i] = f2h(val - h2f(h));
    }
}

// ---------------------------------------------------------------------------
// uxvx GEMM: [80000x64] @ G^T[64x32] -> uxc (cols 0..8, +c) / vxp (cols 9..17).
// f16 hi/lo split keeps logits fp32-accurate.
// ---------------------------------------------------------------------------
__global__ __launch_bounds__(256) void uxvx_kernel(
    const u16* __restrict__ xh, const u16* __restrict__ xl,
    const u16* __restrict__ Gh, const u16* __restrict__ Gl,
    const float* __restrict__ c, float* __restrict__ uxc, float* __restrict__ vxp)
{
    const int wave = threadIdx.x >> 6, lane = threadIdx.x & 63;
    const int lr = lane & 15, lhi = lane >> 4;
    const int t0 = blockIdx.x * 64 + wave * 16;

    const u16* xrh = xh + (size_t)(t0 + lr) * 64 + lhi * 8;
    const u16* xrl = xl + (size_t)(t0 + lr) * 64 + lhi * 8;
    f16x8 ah0 = *(const f16x8*)(xrh), ah1 = *(const f16x8*)(xrh + 32);
    f16x8 al0 = *(const f16x8*)(xrl), al1 = *(const f16x8*)(xrl + 32);

    f32x4 acc0 = {0.f,0.f,0.f,0.f}, acc1 = {0.f,0.f,0.f,0.f};
    #pragma unroll
    for (int t = 0; t < 2; ++t) {
        f32x4 acc = {0.f,0.f,0.f,0.f};
        #pragma unroll
        for (int s = 0; s < 2; ++s) {
            f16x8 gh = *(const f16x8*)(Gh + (t * 16 + lr) * 64 + s * 32 + lhi * 8);
            f16x8 gl = *(const f16x8*)(Gl + (t * 16 + lr) * 64 + s * 32 + lhi * 8);
            f16x8 as  = s ? ah1 : ah0;
            f16x8 asl = s ? al1 : al0;
            acc = __builtin_amdgcn_mfma_f32_16x16x32_f16(as,  gh, acc, 0, 0, 0);
            acc = __builtin_amdgcn_mfma_f32_16x16x32_f16(as,  gl, acc, 0, 0, 0);
            acc = __builtin_amdgcn_mfma_f32_16x16x32_f16(asl, gh, acc, 0, 0, 0);
        }
        if (t == 0) acc0 = acc; else acc1 = acc;
    }

    float cv = (lr < 9) ? c[lr] : 0.f;
    #pragma unroll
    for (int reg = 0; reg < 4; ++reg) {
        int node = t0 + lhi * 4 + reg;
        if (lr < 9) uxc[(size_t)node * UVP + lr] = acc0[reg] + cv;
        else        vxp[(size_t)node * UVP + (lr - 9)] = acc0[reg];
        if (lr < 2) vxp[(size_t)node * UVP + 7 + lr] = acc1[reg];
    }
}

// ---------------------------------------------------------------------------
// Fused: block = 4 waves = 16 nodes.
// Phase A: lane=(g,k); softmax over M; inv_deg folded into q; q -> qlds f16
//          [node][m][k] (k contiguous). No zero-init needed: garbage in m>=9
//          B-columns stays in discarded D2 columns (MFMA cols don't mix).
// Phase B: MFMA-transpose trick. Per node:
//          (1) natural gather: lane (lr,lhi) loads x[edge(lr)][lhi*8+j] as
//              dwordx4 -> A-frag of transpose-MFMA (2 loads cover c 0..63).
//          (2) D = Xnat @ Isel (16x16x32): D[edge][c] in D-layout = lane
//              c=lane&15, edge=(lane>>4)*4+reg == A-frag of 16x16x16.
//              pkrtz re-pack is exact (values are exact f16).
//          (3) D2[c][m] = Xt @ Q (16x16x16, k=16 edges, no padding waste);
//              Q B-frag = one ds_read_b64 per node.
//          (4) D2 (lr=m<9, rows=c) -> slds [node][m][c] via RNE cvt + b64.
// Phase C: out[16x64] = s[16x576] @ W'[576x64] + bias (unchanged, verified).
// Layouts (m89/m101/m121-128 verified, dtype-independent):
//   16x16x32: A row=lane&15, k=(lane>>4)*8+j; 16x16x16: A row=lane&15,
//   k=(lane>>4)*4+j; B mirrors A with col=lane&15; D col=lane&15,
//   row=(lane>>4)*4+reg (both shapes).
// ---------------------------------------------------------------------------
__global__ __launch_bounds__(256) void fused_kernel(
    const u16* __restrict__ xh, const int* __restrict__ adj,
    const float* __restrict__ uxc, const float* __restrict__ vxp,
    const u16* __restrict__ wfb2, const float* __restrict__ bias,
    float* __restrict__ out)
{
    __shared__ __align__(16) u16 qlds[16 * QNP];   //  8704 B
    __shared__ __align__(16) u16 slds[16 * SNP];   // 20736 B
    const int tid = threadIdx.x, wave = tid >> 6, lane = tid & 63;
    const int lr = lane & 15, lhi = lane >> 4;
    const int node0 = blockIdx.x * 16;
    const int b = node0 / NN;
    const int rowbase = b * NN;

    // ---- Phase A ----
    const int g = lhi;                        // node-local within wave
    const int k = lr;                         // neighbor index
    const int node = node0 + wave * 4 + g;
    int jj = adj[(size_t)node0 * KK + tid];   // coalesced; lane (g,k) owns edge
    unsigned long long bal = __ballot(jj != 0);
    int deg = __popcll((bal >> (g * 16)) & 0xffffull);
    float inv = (deg > 0) ? (1.0f / (float)deg) : 0.0f;

    float q[MM];
    #pragma unroll
    for (int m = 0; m < MM; ++m) q[m] = 0.f;
    if (jj != 0) {
        const float4* ur = (const float4*)(uxc + (size_t)node * UVP);
        const float4* vr = (const float4*)(vxp + ((size_t)rowbase + (jj - 1)) * UVP);
        float4 u0 = ur[0], u1 = ur[1], u2 = ur[2];
        float4 v0 = vr[0], v1 = vr[1], v2 = vr[2];
        float l[MM] = { u0.x+v0.x, u0.y+v0.y, u0.z+v0.z, u0.w+v0.w,
                        u1.x+v1.x, u1.y+v1.y, u1.z+v1.z, u1.w+v1.w,
                        u2.x+v2.x };
        float mx = l[0];
        #pragma unroll
        for (int m = 1; m < MM; ++m) mx = fmaxf(mx, l[m]);
        float sum = 0.f;
        #pragma unroll
        for (int m = 0; m < MM; ++m) { l[m] = __expf(l[m] - mx); sum += l[m]; }
        float sc = inv / sum;
        #pragma unroll
        for (int m = 0; m < MM; ++m) q[m] = l[m] * sc;
    }
    {   // q -> qlds [node][m*16 + k]; consumed by same wave (LDS per-wave in-order)
        u16* qw = qlds + (wave * 4 + g) * QNP + k;
        #pragma unroll
        for (int m = 0; m < MM; ++m) qw[m * 16] = f2h(q[m]);
    }

    // identity-selector B-frags for the transpose-MFMA: Isel[c'][col]=1 iff
    // c' == s*16+col; lane (col=lr, khi=lhi) elem j -> c'=lhi*8+j
    f16x8 idf[2];
    #pragma unroll
    for (int s = 0; s < 2; ++s) {
        union { u16 us[8]; f16x8 v; } t;
        #pragma unroll
        for (int j = 0; j < 8; ++j)
            t.us[j] = (lhi * 8 + j == s * 16 + lr) ? (u16)0x3C00 : (u16)0;
        idf[s] = t.v;
    }

    // ---- Phase B ----
    const u16* xhb = xh + ((size_t)rowbase << 6);
    #pragma unroll 1
    for (int g2 = 0; g2 < 4; ++g2) {
        const int rnode = wave * 4 + g2;
        // edge row for this lane's A-row (lr): bpermute from wave-resident adj
        int e = __builtin_amdgcn_ds_bpermute((g2 * 16 + lr) * 4, jj);
        int erow = ((e > 0) ? e : 1) - 1;              // pad -> row 0 (q=0 kills)
        const u16* rp = xhb + ((size_t)erow << 6) + lhi * 8;
        f16x8 aLo = *(const f16x8*)(rp);               // c 0..31 slice (j-run)
        f16x8 aHi = *(const f16x8*)(rp + 32);          // c 32..63 slice
        // Q B-frag (16x16x16): lane (col=m=lr, khi=lhi) elems j -> k=lhi*4+j
        f16x4 qf = *(const f16x4*)(qlds + rnode * QNP + lr * 16 + lhi * 4);

        #pragma unroll
        for (int cc = 0; cc < 4; ++cc) {
            // transpose: D[edge][c] = Xnat(32 c') @ Isel
            f32x4 xt = {0.f,0.f,0.f,0.f};
            xt = __builtin_amdgcn_mfma_f32_16x16x32_f16(
                     (cc < 2) ? aLo : aHi, idf[cc & 1], xt, 0, 0, 0);
            // repack D -> A-frag of 16x16x16 (exact: values are exact f16)
            union { fp16v2 h2[2]; f16x4 h4; } at;
            at.h2[0] = __builtin_amdgcn_cvt_pkrtz(xt[0], xt[1]);
            at.h2[1] = __builtin_amdgcn_cvt_pkrtz(xt[2], xt[3]);
            // s-contraction: D2[c][m] = Xt[c][k=16 edges] @ Q[k][m]
            f32x4 d2 = {0.f,0.f,0.f,0.f};
            d2 = __builtin_amdgcn_mfma_f32_16x16x16f16(at.h4, qf, d2, 0, 0, 0);
            if (lr < 9) {   // col=m=lr; rows c = cc*16 + lhi*4 + reg (RNE cvt)
                u32 lo = __builtin_amdgcn_perm((u32)f2h(d2[1]), (u32)f2h(d2[0]), 0x05040100u);
                u32 hi = __builtin_amdgcn_perm((u32)f2h(d2[3]), (u32)f2h(d2[2]), 0x05040100u);
                uint2* p = (uint2*)(slds + rnode * SNP + lr * SCP + cc * 16 + lhi * 4);
                *p = make_uint2(lo, hi);
            }
        }
    }
    __syncthreads();

    // ---- Phase C: out[16 nodes][o-slice] = s @ W' + bias ----
    const int o0 = wave * 16;
    f32x4 acc = {0.f,0.f,0.f,0.f};
    #pragma unroll
    for (int ks = 0; ks < NKS; ++ks) {
        int kf = ks * 32 + lhi * 8;
        int m = kf >> 6, coff = kf & 63;
        f16x8 afrag = *(const f16x8*)(slds + lr * SNP + m * SCP + coff);
        f16x8 bfrag = *(const f16x8*)(wfb2 + (size_t)(((ks * 4 + lhi) * 64) + o0 + lr) * 8);
        acc = __builtin_amdgcn_mfma_f32_16x16x32_f16(afrag, bfrag, acc, 0, 0, 0);
    }
    float bv = bias[o0 + lr];
    #pragma unroll
    for (int reg = 0; reg < 4; ++reg) {
        int rr = node0 + lhi * 4 + reg;
        out[(size_t)rr * OO + o0 + lr] = acc[reg] + bv;
    }
}

// ---------------------------------------------------------------------------
extern "C" void kernel_launch(void* const* d_in, const int* in_sizes, int n_in,
                              void* d_out, int out_size, void* d_ws, size_t ws_size,
                              hipStream_t stream)
{
    const float* x   = (const float*)d_in[0];
    const int*   adj = (const int*)  d_in[1];
    const float* W   = (const float*)d_in[2];
    const float* b   = (const float*)d_in[3];
    const float* u   = (const float*)d_in[4];
    const float* v   = (const float*)d_in[5];
    const float* c   = (const float*)d_in[6];
    float* out = (float*)d_out;

    // workspace layout (16B-aligned sections):
    //   uxc f32 [BN*12] | vxp f32 [BN*12] | xh f16 [BN*64] | xl f16 [BN*64]
    //   wfb2 f16 [36864] | Gh/Gl f16 [2048]       total ~28.3 MB
    float* uxc = (float*)d_ws;
    float* vxp = uxc + (size_t)BN * UVP;
    u16*   xh  = (u16*)(vxp + (size_t)BN * UVP);
    u16*   xl  = xh + (size_t)BN * CC;
    u16*   wfb2= xl + (size_t)BN * CC;
    u16*   Gh  = wfb2 + (size_t)NKS * 2048;
    u16*   Gl  = Gh + 2048;

    setup_kernel<<<5152, 256, 0, stream>>>(x, W, u, v, xh, xl, wfb2, Gh, Gl);
    uxvx_kernel<<<1250, 256, 0, stream>>>(xh, xl, Gh, Gl, c, uxc, vxp);
    fused_kernel<<<5000, 256, 0, stream>>>(xh, adj, uxc, vxp, wfb2, b, out);
}

// Round 7
// 139.023 us; speedup vs baseline: 1.9400x; 1.0114x over previous
//
#include <hip/hip_runtime.h>
#include <cstdint>
#include <cstddef>

// Problem constants
#define BB 4
#define NN 20000
#define KK 16
#define MM 9
#define CC 64
#define OO 64
#define BN (BB*NN)       // 80000 nodes
#define MC (MM*CC)       // 576 flattened reduction dim
#define UVP 12           // padded ux/vx row (9 used + 3 pad) fp32
#define QNP 160          // qlds node pitch (u16); reads up to 255 bleed into
                         // next node / +96 tail pad -> discarded cols, harmless
#define SCP 72           // slds c-pitch per m-row (u16)
#define SNP (MM*SCP)     // 648 u16 per node
#define NKS (MC/32)      // 18 K-steps in Phase C

typedef _Float16 f16x8 __attribute__((ext_vector_type(8)));
typedef _Float16 f16x4 __attribute__((ext_vector_type(4)));
typedef __fp16   fp16v2 __attribute__((ext_vector_type(2)));   // pkrtz return type
typedef float    f32x4 __attribute__((ext_vector_type(4)));
typedef unsigned short u16;
typedef unsigned int   u32;

union Hcv { _Float16 h; u16 u; };
__device__ __forceinline__ u16 f2h(float f) { Hcv t; t.h = (_Float16)f; return t.u; }
__device__ __forceinline__ float h2f(u16 h) { Hcv t; t.u = h; return (float)t.h; }

// ---------------------------------------------------------------------------
// Setup: x -> xh f16; W -> wfb2 f16 in fragment order [ks][lhi][o][8j];
// (u,v) -> G[32][64] f16 hi/lo.
// ---------------------------------------------------------------------------
__global__ __launch_bounds__(256) void setup_kernel(
    const float* __restrict__ x, const float* __restrict__ W,
    const float* __restrict__ u, const float* __restrict__ v,
    u16* __restrict__ xh, u16* __restrict__ wfb2,
    u16* __restrict__ Gh, u16* __restrict__ Gl)
{
    int bid = blockIdx.x;
    if (bid < 5000) {                        // x cvt: 5000*1024 = 5.12M elems
        int i = bid * 1024 + threadIdx.x * 4;
        float4 xv = *(const float4*)(x + i);
        ushort4 hv;
        hv.x = f2h(xv.x); hv.y = f2h(xv.y); hv.z = f2h(xv.z); hv.w = f2h(xv.w);
        *(ushort4*)(xh + i) = hv;
    } else if (bid < 5144) {                 // W swizzle: 144*256 = 36864 elems
        int i = (bid - 5000) * 256 + threadIdx.x;
        int j = i & 7, o = (i >> 3) & 63, lhi = (i >> 9) & 3, ks = i >> 11;
        int kf = ks * 32 + lhi * 8 + j;
        int m = kf >> 6, cc = kf & 63;
        wfb2[i] = f2h(W[m * 4096 + o * 64 + cc]);
    } else {                                 // G build: 8*256 = 2048 elems
        int i = (bid - 5144) * 256 + threadIdx.x;
        int r = i >> 6, cc = i & 63;
        float val = (r < 9) ? u[r * 64 + cc] : ((r < 18) ? v[(r - 9) * 64 + cc] : 0.f);
        u16 h = f2h(val);
        Gh[i] = h;
        Gl[i] = f2h(val - h2f(h));
    }
}

// ---------------------------------------------------------------------------
// uxvx GEMM: [80000x64] @ G^T[64x32] -> uxc (cols 0..8, +c) / vxp (cols 9..17).
// Reads fp32 x directly, hi/lo f16 split in-register (fp32-accurate logits).
// ---------------------------------------------------------------------------
__global__ __launch_bounds__(256) void uxvx_kernel(
    const float* __restrict__ x,
    const u16* __restrict__ Gh, const u16* __restrict__ Gl,
    const float* __restrict__ c, float* __restrict__ uxc, float* __restrict__ vxp)
{
    const int wave = threadIdx.x >> 6, lane = threadIdx.x & 63;
    const int lr = lane & 15, lhi = lane >> 4;
    const int t0 = blockIdx.x * 64 + wave * 16;

    const float* xr = x + (size_t)(t0 + lr) * 64 + lhi * 8;
    float xf[16];
    *(float4*)(xf + 0)  = *(const float4*)(xr + 0);
    *(float4*)(xf + 4)  = *(const float4*)(xr + 4);
    *(float4*)(xf + 8)  = *(const float4*)(xr + 32);
    *(float4*)(xf + 12) = *(const float4*)(xr + 36);
    union { u16 us[8]; f16x8 v; } H0, L0, H1, L1;
    #pragma unroll
    for (int i = 0; i < 8; ++i) {
        u16 h = f2h(xf[i]);      H0.us[i] = h; L0.us[i] = f2h(xf[i] - h2f(h));
        u16 h2 = f2h(xf[8 + i]); H1.us[i] = h2; L1.us[i] = f2h(xf[8 + i] - h2f(h2));
    }

    f32x4 acc0 = {0.f,0.f,0.f,0.f}, acc1 = {0.f,0.f,0.f,0.f};
    #pragma unroll
    for (int t = 0; t < 2; ++t) {
        f32x4 acc = {0.f,0.f,0.f,0.f};
        #pragma unroll
        for (int s = 0; s < 2; ++s) {
            f16x8 gh = *(const f16x8*)(Gh + (t * 16 + lr) * 64 + s * 32 + lhi * 8);
            f16x8 gl = *(const f16x8*)(Gl + (t * 16 + lr) * 64 + s * 32 + lhi * 8);
            f16x8 as  = s ? H1.v : H0.v;
            f16x8 asl = s ? L1.v : L0.v;
            acc = __builtin_amdgcn_mfma_f32_16x16x32_f16(as,  gh, acc, 0, 0, 0);
            acc = __builtin_amdgcn_mfma_f32_16x16x32_f16(as,  gl, acc, 0, 0, 0);
            acc = __builtin_amdgcn_mfma_f32_16x16x32_f16(asl, gh, acc, 0, 0, 0);
        }
        if (t == 0) acc0 = acc; else acc1 = acc;
    }

    float cv = (lr < 9) ? c[lr] : 0.f;
    #pragma unroll
    for (int reg = 0; reg < 4; ++reg) {
        int node = t0 + lhi * 4 + reg;
        if (lr < 9) uxc[(size_t)node * UVP + lr] = acc0[reg] + cv;
        else        vxp[(size_t)node * UVP + (lr - 9)] = acc0[reg];
        if (lr < 2) vxp[(size_t)node * UVP + 7 + lr] = acc1[reg];
    }
}

// ---------------------------------------------------------------------------
// Fused: block = 4 waves = 16 nodes.
// Phase A: lane=(g,k); softmax over M; inv_deg folded into q; q -> qlds f16
//          [node][m][k]. Garbage in m>=9 B-cols stays in discarded D2 cols.
// Phase B: MFMA-transpose, software-pipelined: ALL 4 nodes' bpermutes, qf
//          ds_reads, and x-gathers issue before any compute (4 serial gather
//          latencies -> 1). Then per node: D=Xnat@Isel (transpose),
//          D2[c][m]=Xt@Q (16x16x16), D2 -> slds with XOR-32 c-swizzle keyed
//          by node bit 3 (kills Phase C lr<->lr+8 b128 bank alias; write side
//          swizzle is wave-uniform -> write pattern unchanged).
// Phase C: out[16x64] = s[16x576] @ W'[576x64] + bias; afrag c-offset XORed
//          by ((lr>>3)&1)*32 to match.
// Layouts (m89/m101/m121-128 verified, dtype-independent):
//   16x16x32: A row=lane&15, k=(lane>>4)*8+j; 16x16x16: A row=lane&15,
//   k=(lane>>4)*4+j; B mirrors A with col=lane&15; D col=lane&15,
//   row=(lane>>4)*4+reg (both shapes).
// ---------------------------------------------------------------------------
__global__ __launch_bounds__(256) void fused_kernel(
    const u16* __restrict__ xh, const int* __restrict__ adj,
    const float* __restrict__ uxc, const float* __restrict__ vxp,
    const u16* __restrict__ wfb2, const float* __restrict__ bias,
    float* __restrict__ out)
{
    __shared__ __align__(16) u16 qlds[16 * QNP + 96];  //  5312 B
    __shared__ __align__(16) u16 slds[16 * SNP];       // 20736 B (tot 26 KB -> 6 blk/CU)
    const int tid = threadIdx.x, wave = tid >> 6, lane = tid & 63;
    const int lr = lane & 15, lhi = lane >> 4;
    const int node0 = blockIdx.x * 16;
    const int b = node0 / NN;
    const int rowbase = b * NN;

    // ---- Phase A ----
    const int g = lhi;                        // node-local within wave
    const int k = lr;                         // neighbor index
    const int node = node0 + wave * 4 + g;
    int jj = adj[(size_t)node0 * KK + tid];   // coalesced; lane (g,k) owns edge
    unsigned long long bal = __ballot(jj != 0);
    int deg = __popcll((bal >> (g * 16)) & 0xffffull);
    float inv = (deg > 0) ? (1.0f / (float)deg) : 0.0f;

    float q[MM];
    #pragma unroll
    for (int m = 0; m < MM; ++m) q[m] = 0.f;
    if (jj != 0) {
        const float4* ur = (const float4*)(uxc + (size_t)node * UVP);
        const float4* vr = (const float4*)(vxp + ((size_t)rowbase + (jj - 1)) * UVP);
        float4 u0 = ur[0], u1 = ur[1], u2 = ur[2];
        float4 v0 = vr[0], v1 = vr[1], v2 = vr[2];
        float l[MM] = { u0.x+v0.x, u0.y+v0.y, u0.z+v0.z, u0.w+v0.w,
                        u1.x+v1.x, u1.y+v1.y, u1.z+v1.z, u1.w+v1.w,
                        u2.x+v2.x };
        float mx = l[0];
        #pragma unroll
        for (int m = 1; m < MM; ++m) mx = fmaxf(mx, l[m]);
        float sum = 0.f;
        #pragma unroll
        for (int m = 0; m < MM; ++m) { l[m] = __expf(l[m] - mx); sum += l[m]; }
        float sc = inv / sum;
        #pragma unroll
        for (int m = 0; m < MM; ++m) q[m] = l[m] * sc;
    }
    {   // q -> qlds [node][m*16 + k]; consumed by same wave (per-wave in-order)
        u16* qw = qlds + (wave * 4 + g) * QNP + k;
        #pragma unroll
        for (int m = 0; m < MM; ++m) qw[m * 16] = f2h(q[m]);
    }

    // identity-selector B-frags for the transpose-MFMA: Isel[c'][col]=1 iff
    // c' == s*16+col; lane (col=lr, khi=lhi) elem j -> c'=lhi*8+j
    f16x8 idf[2];
    #pragma unroll
    for (int s = 0; s < 2; ++s) {
        union { u16 us[8]; f16x8 v; } t;
        #pragma unroll
        for (int j = 0; j < 8; ++j)
            t.us[j] = (lhi * 8 + j == s * 16 + lr) ? (u16)0x3C00 : (u16)0;
        idf[s] = t.v;
    }

    // ---- Phase B load pass: everything in flight before any compute ----
    const u16* xhb = xh + ((size_t)rowbase << 6);
    f16x8 aLo[4], aHi[4];
    f16x4 qf[4];
    #pragma unroll
    for (int g2 = 0; g2 < 4; ++g2) {
        int e = __builtin_amdgcn_ds_bpermute((g2 * 16 + lr) * 4, jj);
        int erow = ((e > 0) ? e : 1) - 1;              // pad -> row 0 (q=0 kills)
        const u16* rp = xhb + ((size_t)erow << 6) + lhi * 8;
        aLo[g2] = *(const f16x8*)(rp);                 // c 0..31 slice (j-run)
        aHi[g2] = *(const f16x8*)(rp + 32);            // c 32..63 slice
        qf[g2]  = *(const f16x4*)(qlds + (wave * 4 + g2) * QNP + lr * 16 + lhi * 4);
    }

    // ---- Phase B compute pass ----
    #pragma unroll
    for (int g2 = 0; g2 < 4; ++g2) {
        const int rnode = wave * 4 + g2;
        const int swz = ((rnode >> 3) & 1) * 32;       // wave-uniform
        #pragma unroll
        for (int cc = 0; cc < 4; ++cc) {
            // transpose: D[edge][c] = Xnat(32 c') @ Isel
            f32x4 xt = {0.f,0.f,0.f,0.f};
            xt = __builtin_amdgcn_mfma_f32_16x16x32_f16(
                     (cc < 2) ? aLo[g2] : aHi[g2], idf[cc & 1], xt, 0, 0, 0);
            // repack D -> A-frag of 16x16x16 (exact: values are exact f16)
            union { fp16v2 h2[2]; f16x4 h4; } at;
            at.h2[0] = __builtin_amdgcn_cvt_pkrtz(xt[0], xt[1]);
            at.h2[1] = __builtin_amdgcn_cvt_pkrtz(xt[2], xt[3]);
            // s-contraction: D2[c][m] = Xt[c][k=16 edges] @ Q[k][m]
            f32x4 d2 = {0.f,0.f,0.f,0.f};
            d2 = __builtin_amdgcn_mfma_f32_16x16x16f16(at.h4, qf[g2], d2, 0, 0, 0);
            if (lr < 9) {   // col=m=lr; rows c = cc*16 + lhi*4 + reg (RNE cvt)
                u32 lo = __builtin_amdgcn_perm((u32)f2h(d2[1]), (u32)f2h(d2[0]), 0x05040100u);
                u32 hi = __builtin_amdgcn_perm((u32)f2h(d2[3]), (u32)f2h(d2[2]), 0x05040100u);
                uint2* p = (uint2*)(slds + rnode * SNP + lr * SCP
                                    + ((cc * 16 + lhi * 4) ^ swz));
                *p = make_uint2(lo, hi);
            }
        }
    }
    __syncthreads();

    // ---- Phase C: out[16 nodes][o-slice] = s @ W' + bias ----
    const int o0 = wave * 16;
    const int swzR = ((lr >> 3) & 1) * 32;
    f32x4 acc = {0.f,0.f,0.f,0.f};
    #pragma unroll
    for (int ks = 0; ks < NKS; ++ks) {
        int kf = ks * 32 + lhi * 8;
        int m = kf >> 6, coff = kf & 63;
        f16x8 afrag = *(const f16x8*)(slds + lr * SNP + m * SCP + (coff ^ swzR));
        f16x8 bfrag = *(const f16x8*)(wfb2 + (size_t)(((ks * 4 + lhi) * 64) + o0 + lr) * 8);
        acc = __builtin_amdgcn_mfma_f32_16x16x32_f16(afrag, bfrag, acc, 0, 0, 0);
    }
    float bv = bias[o0 + lr];
    #pragma unroll
    for (int reg = 0; reg < 4; ++reg) {
        int rr = node0 + lhi * 4 + reg;
        out[(size_t)rr * OO + o0 + lr] = acc[reg] + bv;
    }
}

// ---------------------------------------------------------------------------
extern "C" void kernel_launch(void* const* d_in, const int* in_sizes, int n_in,
                              void* d_out, int out_size, void* d_ws, size_t ws_size,
                              hipStream_t stream)
{
    const float* x   = (const float*)d_in[0];
    const int*   adj = (const int*)  d_in[1];
    const float* W   = (const float*)d_in[2];
    const float* b   = (const float*)d_in[3];
    const float* u   = (const float*)d_in[4];
    const float* v   = (const float*)d_in[5];
    const float* c   = (const float*)d_in[6];
    float* out = (float*)d_out;

    // workspace layout (16B-aligned sections):
    //   uxc f32 [BN*12] | vxp f32 [BN*12] | xh f16 [BN*64]
    //   wfb2 f16 [36864] | Gh/Gl f16 [2048]       total ~18 MB
    float* uxc = (float*)d_ws;
    float* vxp = uxc + (size_t)BN * UVP;
    u16*   xh  = (u16*)(vxp + (size_t)BN * UVP);
    u16*   wfb2= xh + (size_t)BN * CC;
    u16*   Gh  = wfb2 + (size_t)NKS * 2048;
    u16*   Gl  = Gh + 2048;

    setup_kernel<<<5152, 256, 0, stream>>>(x, W, u, v, xh, wfb2, Gh, Gl);
    uxvx_kernel<<<1250, 256, 0, stream>>>(x, Gh, Gl, c, uxc, vxp);
    fused_kernel<<<5000, 256, 0, stream>>>(xh, adj, uxc, vxp, wfb2, b, out);
}

// Round 9
// 133.552 us; speedup vs baseline: 2.0195x; 1.0410x over previous
//
#include <hip/hip_runtime.h>
#include <cstdint>
#include <cstddef>

// Problem constants
#define BB 4
#define NN 20000
#define KK 16
#define MM 9
#define CC 64
#define OO 64
#define BN (BB*NN)       // 80000 nodes
#define MC (MM*CC)       // 576 flattened reduction dim
#define UVP 12           // padded ux/vx row (9 used + 3 pad) fp32
#define QNP 272          // qlds node pitch (u16): 136 dw == 8 mod 32 -> Phase A
                         // write banks spread across the 4 node-groups (R6-verified)
#define SCP 72           // slds c-pitch per m-row (u16)
#define SNP (MM*SCP)     // 648 u16 per node
#define NKS (MC/32)      // 18 K-steps in Phase C

typedef _Float16 f16x8 __attribute__((ext_vector_type(8)));
typedef _Float16 f16x4 __attribute__((ext_vector_type(4)));
typedef __fp16   fp16v2 __attribute__((ext_vector_type(2)));   // pkrtz return type
typedef float    f32x4 __attribute__((ext_vector_type(4)));
typedef unsigned short u16;
typedef unsigned int   u32;

union Hcv { _Float16 h; u16 u; };
__device__ __forceinline__ u16 f2h(float f) { Hcv t; t.h = (_Float16)f; return t.u; }
__device__ __forceinline__ float h2f(u16 h) { Hcv t; t.u = h; return (float)t.h; }

// ---------------------------------------------------------------------------
// Pre-pass (merged): blocks < 1250: uxvx GEMM for 64 nodes AND xh side-write
// (x is already loaded + f16-split for the MFMA A-operand — store it).
// G fragments built in-register from u/v (no cross-block dependency).
// Blocks 1250..1285: W -> wfb2 fragment-order swizzle (independent).
// ---------------------------------------------------------------------------
__global__ __launch_bounds__(256) void pre_kernel(
    const float* __restrict__ x, const float* __restrict__ W,
    const float* __restrict__ u, const float* __restrict__ v,
    const float* __restrict__ c,
    float* __restrict__ uxc, float* __restrict__ vxp,
    u16* __restrict__ xh, u16* __restrict__ wfb2)
{
    const int bid = blockIdx.x;
    if (bid >= 1250) {                        // W swizzle: 36*1024 = 36864 elems
        int base = (bid - 1250) * 1024 + threadIdx.x * 4;
        ushort4 wv;
        u16* wp = (u16*)&wv;
        #pragma unroll
        for (int t = 0; t < 4; ++t) {
            int i = base + t;
            int j = i & 7, o = (i >> 3) & 63, l2 = (i >> 9) & 3, ks = i >> 11;
            int kf = ks * 32 + l2 * 8 + j;
            int m = kf >> 6, cc2 = kf & 63;
            wp[t] = f2h(W[m * 4096 + o * 64 + cc2]);
        }
        *(ushort4*)(wfb2 + base) = wv;
        return;
    }
    const int wave = threadIdx.x >> 6, lane = threadIdx.x & 63;
    const int lr = lane & 15, lhi = lane >> 4;
    const int t0n = bid * 64 + wave * 16;

    // x rows: lane covers node t0n+lr, cols [lhi*8,+8) and [32+lhi*8,+8)
    const float* xr = x + (size_t)(t0n + lr) * 64 + lhi * 8;
    float xf[16];
    *(float4*)(xf + 0)  = *(const float4*)(xr + 0);
    *(float4*)(xf + 4)  = *(const float4*)(xr + 4);
    *(float4*)(xf + 8)  = *(const float4*)(xr + 32);
    *(float4*)(xf + 12) = *(const float4*)(xr + 36);
    union { u16 us[8]; f16x8 v; ushort4 s4[2]; } H0, L0, H1, L1;
    #pragma unroll
    for (int i = 0; i < 8; ++i) {
        u16 h = f2h(xf[i]);      H0.us[i] = h;  L0.us[i] = f2h(xf[i] - h2f(h));
        u16 h2 = f2h(xf[8 + i]); H1.us[i] = h2; L1.us[i] = f2h(xf[8 + i] - h2f(h2));
    }
    // xh side-write (16B per half)
    *(ushort4*)(xh + (size_t)(t0n + lr) * 64 + lhi * 8)      = H0.s4[0];
    *(ushort4*)(xh + (size_t)(t0n + lr) * 64 + lhi * 8 + 4)  = H0.s4[1];
    *(ushort4*)(xh + (size_t)(t0n + lr) * 64 + 32 + lhi * 8)     = H1.s4[0];
    *(ushort4*)(xh + (size_t)(t0n + lr) * 64 + 32 + lhi * 8 + 4) = H1.s4[1];

    // uxvx: acc[t] = X[16x64] @ G^T where G row r = t*16+lr: u[r] / v[r-9] / 0
    f32x4 acc0 = {0.f,0.f,0.f,0.f}, acc1 = {0.f,0.f,0.f,0.f};
    #pragma unroll
    for (int t = 0; t < 2; ++t) {
        int r = t * 16 + lr;
        const float* gp = (r < 9) ? (u + r * 64) : (v + (r - 9) * 64);
        bool nz = r < 18;
        f32x4 acc = {0.f,0.f,0.f,0.f};
        #pragma unroll
        for (int s = 0; s < 2; ++s) {
            float gf[8];
            *(float4*)(gf + 0) = nz ? *(const float4*)(gp + s * 32 + lhi * 8)
                                    : make_float4(0.f,0.f,0.f,0.f);
            *(float4*)(gf + 4) = nz ? *(const float4*)(gp + s * 32 + lhi * 8 + 4)
                                    : make_float4(0.f,0.f,0.f,0.f);
            union { u16 us[8]; f16x8 v; } GH, GL;
            #pragma unroll
            for (int i = 0; i < 8; ++i) {
                u16 h = f2h(gf[i]); GH.us[i] = h; GL.us[i] = f2h(gf[i] - h2f(h));
            }
            f16x8 as  = s ? H1.v : H0.v;
            f16x8 asl = s ? L1.v : L0.v;
            acc = __builtin_amdgcn_mfma_f32_16x16x32_f16(as,  GH.v, acc, 0, 0, 0);
            acc = __builtin_amdgcn_mfma_f32_16x16x32_f16(as,  GL.v, acc, 0, 0, 0);
            acc = __builtin_amdgcn_mfma_f32_16x16x32_f16(asl, GH.v, acc, 0, 0, 0);
        }
        if (t == 0) acc0 = acc; else acc1 = acc;
    }
    float cv = (lr < 9) ? c[lr] : 0.f;
    #pragma unroll
    for (int reg = 0; reg < 4; ++reg) {
        int node = t0n + lhi * 4 + reg;
        if (lr < 9) uxc[(size_t)node * UVP + lr] = acc0[reg] + cv;
        else        vxp[(size_t)node * UVP + (lr - 9)] = acc0[reg];
        if (lr < 2) vxp[(size_t)node * UVP + 7 + lr] = acc1[reg];
    }
}

// ---------------------------------------------------------------------------
// Fused: block = 4 waves = 32 nodes = 2 MFMA tiles, software-pipelined:
//   A(t0,t1) -> Bload(t0) -> Bcomp(t0) -> bar -> Bload(t1)+C(t0) -> bar
//   -> Bcomp(t1) -> bar -> C(t1)
// Bload(t1) targets registers only, so its gather latency hides under C(t0)'s
// 18 MFMAs; slds is reused across tiles (single buffer).
// A block owns 32 nodes = 512 adj entries: tile0 at +0, tile1 at +256
// (16 nodes x K=16 each). [R8 bug: +512 read the next block's adjacency]
// Phase B per node: MFMA-transpose (D=Xnat@Isel) then D2[c][m]=Xt@Q (16x16x16).
// Layouts (m89/m101/m121-128 verified, dtype-independent):
//   16x16x32: A row=lane&15, k=(lane>>4)*8+j; 16x16x16: A row=lane&15,
//   k=(lane>>4)*4+j; B mirrors A with col=lane&15; D col=lane&15,
//   row=(lane>>4)*4+reg (both shapes).
// ---------------------------------------------------------------------------
__global__ __launch_bounds__(256) void fused_kernel(
    const u16* __restrict__ xh, const int* __restrict__ adj,
    const float* __restrict__ uxc, const float* __restrict__ vxp,
    const u16* __restrict__ wfb2, const float* __restrict__ bias,
    float* __restrict__ out)
{
    __shared__ __align__(16) u16 qlds[32 * QNP];   // 17408 B
    __shared__ __align__(16) u16 slds[16 * SNP];   // 20736 B  (38.1 KB -> 4 blk/CU)
    const int tid = threadIdx.x, wave = tid >> 6, lane = tid & 63;
    const int lr = lane & 15, lhi = lane >> 4;
    const int node0 = blockIdx.x * 32;             // 32 | 20000 -> single batch
    const int b = node0 / NN;
    const int rowbase = b * NN;
    const u16* xhb = xh + ((size_t)rowbase << 6);

    // ---- Phase A (both tiles) ----
    const int g = lhi;                             // node-local within wave
    const int k = lr;                              // neighbor index
    int jjA[2];
    jjA[0] = adj[(size_t)node0 * KK + tid];        // tile0: entries [0,256)
    jjA[1] = adj[(size_t)node0 * KK + 256 + tid];  // tile1: entries [256,512)
    #pragma unroll
    for (int t = 0; t < 2; ++t) {
        int jj = jjA[t];
        unsigned long long bal = __ballot(jj != 0);
        int deg = __popcll((bal >> (g * 16)) & 0xffffull);
        float inv = (deg > 0) ? (1.0f / (float)deg) : 0.0f;
        const int node = node0 + t * 16 + wave * 4 + g;
        float q[MM];
        #pragma unroll
        for (int m = 0; m < MM; ++m) q[m] = 0.f;
        if (jj != 0) {
            const float4* ur = (const float4*)(uxc + (size_t)node * UVP);
            const float4* vr = (const float4*)(vxp + ((size_t)rowbase + (jj - 1)) * UVP);
            float4 u0 = ur[0], u1 = ur[1], u2 = ur[2];
            float4 v0 = vr[0], v1 = vr[1], v2 = vr[2];
            float l[MM] = { u0.x+v0.x, u0.y+v0.y, u0.z+v0.z, u0.w+v0.w,
                            u1.x+v1.x, u1.y+v1.y, u1.z+v1.z, u1.w+v1.w,
                            u2.x+v2.x };
            float mx = l[0];
            #pragma unroll
            for (int m = 1; m < MM; ++m) mx = fmaxf(mx, l[m]);
            float sum = 0.f;
            #pragma unroll
            for (int m = 0; m < MM; ++m) { l[m] = __expf(l[m] - mx); sum += l[m]; }
            float sc = inv / sum;
            #pragma unroll
            for (int m = 0; m < MM; ++m) q[m] = l[m] * sc;
        }
        u16* qw = qlds + (t * 16 + wave * 4 + g) * QNP + k;
        #pragma unroll
        for (int m = 0; m < MM; ++m) qw[m * 16] = f2h(q[m]);
    }

    // identity-selector B-frags for the transpose-MFMA
    f16x8 idf[2];
    #pragma unroll
    for (int s = 0; s < 2; ++s) {
        union { u16 us[8]; f16x8 v; } t;
        #pragma unroll
        for (int j = 0; j < 8; ++j)
            t.us[j] = (lhi * 8 + j == s * 16 + lr) ? (u16)0x3C00 : (u16)0;
        idf[s] = t.v;
    }

    // ---- Bload(t0) ----
    f16x8 aLo[4], aHi[4];
    f16x4 qf[4];
    #pragma unroll
    for (int g2 = 0; g2 < 4; ++g2) {
        int e = __builtin_amdgcn_ds_bpermute((g2 * 16 + lr) * 4, jjA[0]);
        int erow = ((e > 0) ? e : 1) - 1;          // pad -> row 0 (q=0 kills)
        const u16* rp = xhb + ((size_t)erow << 6) + lhi * 8;
        aLo[g2] = *(const f16x8*)(rp);
        aHi[g2] = *(const f16x8*)(rp + 32);
        qf[g2]  = *(const f16x4*)(qlds + (wave * 4 + g2) * QNP + lr * 16 + lhi * 4);
    }

    // ---- Bcomp(t0) -> slds ----
    #pragma unroll
    for (int g2 = 0; g2 < 4; ++g2) {
        const int rnode = wave * 4 + g2;
        #pragma unroll
        for (int cc = 0; cc < 4; ++cc) {
            f32x4 xt = {0.f,0.f,0.f,0.f};
            xt = __builtin_amdgcn_mfma_f32_16x16x32_f16(
                     (cc < 2) ? aLo[g2] : aHi[g2], idf[cc & 1], xt, 0, 0, 0);
            union { fp16v2 h2[2]; f16x4 h4; } at;
            at.h2[0] = __builtin_amdgcn_cvt_pkrtz(xt[0], xt[1]);
            at.h2[1] = __builtin_amdgcn_cvt_pkrtz(xt[2], xt[3]);
            f32x4 d2 = {0.f,0.f,0.f,0.f};
            d2 = __builtin_amdgcn_mfma_f32_16x16x16f16(at.h4, qf[g2], d2, 0, 0, 0);
            if (lr < 9) {
                u32 lo = __builtin_amdgcn_perm((u32)f2h(d2[1]), (u32)f2h(d2[0]), 0x05040100u);
                u32 hi = __builtin_amdgcn_perm((u32)f2h(d2[3]), (u32)f2h(d2[2]), 0x05040100u);
                uint2* p = (uint2*)(slds + rnode * SNP + lr * SCP + cc * 16 + lhi * 4);
                *p = make_uint2(lo, hi);
            }
        }
    }
    __syncthreads();

    // ---- Bload(t1): registers only — gather latency hides under C(t0) ----
    f16x8 bLo[4], bHi[4];
    f16x4 qg[4];
    #pragma unroll
    for (int g2 = 0; g2 < 4; ++g2) {
        int e = __builtin_amdgcn_ds_bpermute((g2 * 16 + lr) * 4, jjA[1]);
        int erow = ((e > 0) ? e : 1) - 1;
        const u16* rp = xhb + ((size_t)erow << 6) + lhi * 8;
        bLo[g2] = *(const f16x8*)(rp);
        bHi[g2] = *(const f16x8*)(rp + 32);
        qg[g2]  = *(const f16x4*)(qlds + (16 + wave * 4 + g2) * QNP + lr * 16 + lhi * 4);
    }

    // ---- C(t0) ----
    const int o0 = wave * 16;
    float bv = bias[o0 + lr];
    {
        f32x4 acc = {0.f,0.f,0.f,0.f};
        #pragma unroll
        for (int ks = 0; ks < NKS; ++ks) {
            int kf = ks * 32 + lhi * 8;
            int m = kf >> 6, coff = kf & 63;
            f16x8 afrag = *(const f16x8*)(slds + lr * SNP + m * SCP + coff);
            f16x8 bfrag = *(const f16x8*)(wfb2 + (size_t)(((ks * 4 + lhi) * 64) + o0 + lr) * 8);
            acc = __builtin_amdgcn_mfma_f32_16x16x32_f16(afrag, bfrag, acc, 0, 0, 0);
        }
        #pragma unroll
        for (int reg = 0; reg < 4; ++reg) {
            int rr = node0 + lhi * 4 + reg;
            out[(size_t)rr * OO + o0 + lr] = acc[reg] + bv;
        }
    }
    __syncthreads();   // all waves done reading slds(t0)

    // ---- Bcomp(t1) -> slds ----
    #pragma unroll
    for (int g2 = 0; g2 < 4; ++g2) {
        const int rnode = wave * 4 + g2;
        #pragma unroll
        for (int cc = 0; cc < 4; ++cc) {
            f32x4 xt = {0.f,0.f,0.f,0.f};
            xt = __builtin_amdgcn_mfma_f32_16x16x32_f16(
                     (cc < 2) ? bLo[g2] : bHi[g2], idf[cc & 1], xt, 0, 0, 0);
            union { fp16v2 h2[2]; f16x4 h4; } at;
            at.h2[0] = __builtin_amdgcn_cvt_pkrtz(xt[0], xt[1]);
            at.h2[1] = __builtin_amdgcn_cvt_pkrtz(xt[2], xt[3]);
            f32x4 d2 = {0.f,0.f,0.f,0.f};
            d2 = __builtin_amdgcn_mfma_f32_16x16x16f16(at.h4, qg[g2], d2, 0, 0, 0);
            if (lr < 9) {
                u32 lo = __builtin_amdgcn_perm((u32)f2h(d2[1]), (u32)f2h(d2[0]), 0x05040100u);
                u32 hi = __builtin_amdgcn_perm((u32)f2h(d2[3]), (u32)f2h(d2[2]), 0x05040100u);
                uint2* p = (uint2*)(slds + rnode * SNP + lr * SCP + cc * 16 + lhi * 4);
                *p = make_uint2(lo, hi);
            }
        }
    }
    __syncthreads();

    // ---- C(t1) ----
    {
        f32x4 acc = {0.f,0.f,0.f,0.f};
        #pragma unroll
        for (int ks = 0; ks < NKS; ++ks) {
            int kf = ks * 32 + lhi * 8;
            int m = kf >> 6, coff = kf & 63;
            f16x8 afrag = *(const f16x8*)(slds + lr * SNP + m * SCP + coff);
            f16x8 bfrag = *(const f16x8*)(wfb2 + (size_t)(((ks * 4 + lhi) * 64) + o0 + lr) * 8);
            acc = __builtin_amdgcn_mfma_f32_16x16x32_f16(afrag, bfrag, acc, 0, 0, 0);
        }
        #pragma unroll
        for (int reg = 0; reg < 4; ++reg) {
            int rr = node0 + 16 + lhi * 4 + reg;
            out[(size_t)rr * OO + o0 + lr] = acc[reg] + bv;
        }
    }
}

// ---------------------------------------------------------------------------
extern "C" void kernel_launch(void* const* d_in, const int* in_sizes, int n_in,
                              void* d_out, int out_size, void* d_ws, size_t ws_size,
                              hipStream_t stream)
{
    const float* x   = (const float*)d_in[0];
    const int*   adj = (const int*)  d_in[1];
    const float* W   = (const float*)d_in[2];
    const float* b   = (const float*)d_in[3];
    const float* u   = (const float*)d_in[4];
    const float* v   = (const float*)d_in[5];
    const float* c   = (const float*)d_in[6];
    float* out = (float*)d_out;

    // workspace layout (16B-aligned sections):
    //   uxc f32 [BN*12] | vxp f32 [BN*12] | xh f16 [BN*64] | wfb2 f16 [36864]
    //   total ~18 MB
    float* uxc = (float*)d_ws;
    float* vxp = uxc + (size_t)BN * UVP;
    u16*   xh  = (u16*)(vxp + (size_t)BN * UVP);
    u16*   wfb2= xh + (size_t)BN * CC;

    pre_kernel<<<1286, 256, 0, stream>>>(x, W, u, v, c, uxc, vxp, xh, wfb2);
    fused_kernel<<<2500, 256, 0, stream>>>(xh, adj, uxc, vxp, wfb2, b, out);
}

// Round 10
// 132.964 us; speedup vs baseline: 2.0284x; 1.0044x over previous
//
#include <hip/hip_runtime.h>
#include <cstdint>
#include <cstddef>

// Problem constants
#define BB 4
#define NN 20000
#define KK 16
#define MM 9
#define CC 64
#define OO 64
#define BN (BB*NN)       // 80000 nodes
#define MC (MM*CC)       // 576 flattened reduction dim
#define UVP 12           // padded ux/vx row (9 used + 3 pad) fp32
#define QNP 272          // qlds node pitch (u16)
#define SCP 72           // slds c-pitch per m-row (u16)
#define SNP (MM*SCP)     // 648 u16 per node
#define NKS (MC/32)      // 18 K-steps in Phase C
#define NCHUNK 625       // 32-node chunks per batch

typedef _Float16 f16x8 __attribute__((ext_vector_type(8)));
typedef _Float16 f16x4 __attribute__((ext_vector_type(4)));
typedef __fp16   fp16v2 __attribute__((ext_vector_type(2)));   // pkrtz return type
typedef float    f32x4 __attribute__((ext_vector_type(4)));
typedef unsigned short u16;
typedef unsigned int   u32;

union Hcv { _Float16 h; u16 u; };
__device__ __forceinline__ u16 f2h(float f) { Hcv t; t.h = (_Float16)f; return t.u; }
__device__ __forceinline__ float h2f(u16 h) { Hcv t; t.u = h; return (float)t.h; }

// ---------------------------------------------------------------------------
// Pre-pass (merged): blocks < 1250: uxvx GEMM for 64 nodes AND xh side-write.
// Blocks 1250..1285: W -> wfb2 fragment-order swizzle.
// ---------------------------------------------------------------------------
__global__ __launch_bounds__(256) void pre_kernel(
    const float* __restrict__ x, const float* __restrict__ W,
    const float* __restrict__ u, const float* __restrict__ v,
    const float* __restrict__ c,
    float* __restrict__ uxc, float* __restrict__ vxp,
    u16* __restrict__ xh, u16* __restrict__ wfb2)
{
    const int bid = blockIdx.x;
    if (bid >= 1250) {                        // W swizzle: 36*1024 = 36864 elems
        int base = (bid - 1250) * 1024 + threadIdx.x * 4;
        ushort4 wv;
        u16* wp = (u16*)&wv;
        #pragma unroll
        for (int t = 0; t < 4; ++t) {
            int i = base + t;
            int j = i & 7, o = (i >> 3) & 63, l2 = (i >> 9) & 3, ks = i >> 11;
            int kf = ks * 32 + l2 * 8 + j;
            int m = kf >> 6, cc2 = kf & 63;
            wp[t] = f2h(W[m * 4096 + o * 64 + cc2]);
        }
        *(ushort4*)(wfb2 + base) = wv;
        return;
    }
    const int wave = threadIdx.x >> 6, lane = threadIdx.x & 63;
    const int lr = lane & 15, lhi = lane >> 4;
    const int t0n = bid * 64 + wave * 16;

    const float* xr = x + (size_t)(t0n + lr) * 64 + lhi * 8;
    float xf[16];
    *(float4*)(xf + 0)  = *(const float4*)(xr + 0);
    *(float4*)(xf + 4)  = *(const float4*)(xr + 4);
    *(float4*)(xf + 8)  = *(const float4*)(xr + 32);
    *(float4*)(xf + 12) = *(const float4*)(xr + 36);
    union { u16 us[8]; f16x8 v; ushort4 s4[2]; } H0, L0, H1, L1;
    #pragma unroll
    for (int i = 0; i < 8; ++i) {
        u16 h = f2h(xf[i]);      H0.us[i] = h;  L0.us[i] = f2h(xf[i] - h2f(h));
        u16 h2 = f2h(xf[8 + i]); H1.us[i] = h2; L1.us[i] = f2h(xf[8 + i] - h2f(h2));
    }
    *(ushort4*)(xh + (size_t)(t0n + lr) * 64 + lhi * 8)      = H0.s4[0];
    *(ushort4*)(xh + (size_t)(t0n + lr) * 64 + lhi * 8 + 4)  = H0.s4[1];
    *(ushort4*)(xh + (size_t)(t0n + lr) * 64 + 32 + lhi * 8)     = H1.s4[0];
    *(ushort4*)(xh + (size_t)(t0n + lr) * 64 + 32 + lhi * 8 + 4) = H1.s4[1];

    f32x4 acc0 = {0.f,0.f,0.f,0.f}, acc1 = {0.f,0.f,0.f,0.f};
    #pragma unroll
    for (int t = 0; t < 2; ++t) {
        int r = t * 16 + lr;
        const float* gp = (r < 9) ? (u + r * 64) : (v + (r - 9) * 64);
        bool nz = r < 18;
        f32x4 acc = {0.f,0.f,0.f,0.f};
        #pragma unroll
        for (int s = 0; s < 2; ++s) {
            float gf[8];
            *(float4*)(gf + 0) = nz ? *(const float4*)(gp + s * 32 + lhi * 8)
                                    : make_float4(0.f,0.f,0.f,0.f);
            *(float4*)(gf + 4) = nz ? *(const float4*)(gp + s * 32 + lhi * 8 + 4)
                                    : make_float4(0.f,0.f,0.f,0.f);
            union { u16 us[8]; f16x8 v; } GH, GL;
            #pragma unroll
            for (int i = 0; i < 8; ++i) {
                u16 h = f2h(gf[i]); GH.us[i] = h; GL.us[i] = f2h(gf[i] - h2f(h));
            }
            f16x8 as  = s ? H1.v : H0.v;
            f16x8 asl = s ? L1.v : L0.v;
            acc = __builtin_amdgcn_mfma_f32_16x16x32_f16(as,  GH.v, acc, 0, 0, 0);
            acc = __builtin_amdgcn_mfma_f32_16x16x32_f16(as,  GL.v, acc, 0, 0, 0);
            acc = __builtin_amdgcn_mfma_f32_16x16x32_f16(asl, GH.v, acc, 0, 0, 0);
        }
        if (t == 0) acc0 = acc; else acc1 = acc;
    }
    float cv = (lr < 9) ? c[lr] : 0.f;
    #pragma unroll
    for (int reg = 0; reg < 4; ++reg) {
        int node = t0n + lhi * 4 + reg;
        if (lr < 9) uxc[(size_t)node * UVP + lr] = acc0[reg] + cv;
        else        vxp[(size_t)node * UVP + (lr - 9)] = acc0[reg];
        if (lr < 2) vxp[(size_t)node * UVP + 7 + lr] = acc1[reg];
    }
}

// ---------------------------------------------------------------------------
// Fused (body identical to R9) + XCD-locality block swizzle:
// dispatch is round-robin over 8 XCDs; XCD pair {2b,2b+1} owns batch b so
// each XCD's random-gather working set (xh slice 2.56 MB + vxp slice 0.96 MB)
// fits its 4 MB L2 and stays hot across ~313 blocks. Grid padded to 2504;
// chunk >= 625 exits.
// Pipeline: A(t0,t1) -> Bload(t0) -> Bcomp(t0) -> bar -> Bload(t1)+C(t0)
//   -> bar -> Bcomp(t1) -> bar -> C(t1).
// Layouts (m89/m101/m121-128 verified): 16x16x32: A row=lane&15,
// k=(lane>>4)*8+j; 16x16x16: A row=lane&15, k=(lane>>4)*4+j; B mirrors A
// with col=lane&15; D col=lane&15, row=(lane>>4)*4+reg.
// ---------------------------------------------------------------------------
__global__ __launch_bounds__(256) void fused_kernel(
    const u16* __restrict__ xh, const int* __restrict__ adj,
    const float* __restrict__ uxc, const float* __restrict__ vxp,
    const u16* __restrict__ wfb2, const float* __restrict__ bias,
    float* __restrict__ out)
{
    __shared__ __align__(16) u16 qlds[32 * QNP];   // 17408 B
    __shared__ __align__(16) u16 slds[16 * SNP];   // 20736 B
    const int bid = blockIdx.x;
    const int grp = bid & 7;                       // XCD id (round-robin)
    const int b = grp >> 1;                        // batch owned by XCD pair
    const int chunk = (bid >> 3) * 2 + (grp & 1);
    if (chunk >= NCHUNK) return;                   // uniform whole-block exit
    const int tid = threadIdx.x, wave = tid >> 6, lane = tid & 63;
    const int lr = lane & 15, lhi = lane >> 4;
    const int node0 = b * NN + chunk * 32;
    const int rowbase = b * NN;
    const u16* xhb = xh + ((size_t)rowbase << 6);

    // ---- Phase A (both tiles) ----
    const int g = lhi;                             // node-local within wave
    const int k = lr;                              // neighbor index
    int jjA[2];
    jjA[0] = adj[(size_t)node0 * KK + tid];        // tile0: entries [0,256)
    jjA[1] = adj[(size_t)node0 * KK + 256 + tid];  // tile1: entries [256,512)
    #pragma unroll
    for (int t = 0; t < 2; ++t) {
        int jj = jjA[t];
        unsigned long long bal = __ballot(jj != 0);
        int deg = __popcll((bal >> (g * 16)) & 0xffffull);
        float inv = (deg > 0) ? (1.0f / (float)deg) : 0.0f;
        const int node = node0 + t * 16 + wave * 4 + g;
        float q[MM];
        #pragma unroll
        for (int m = 0; m < MM; ++m) q[m] = 0.f;
        if (jj != 0) {
            const float4* ur = (const float4*)(uxc + (size_t)node * UVP);
            const float4* vr = (const float4*)(vxp + ((size_t)rowbase + (jj - 1)) * UVP);
            float4 u0 = ur[0], u1 = ur[1], u2 = ur[2];
            float4 v0 = vr[0], v1 = vr[1], v2 = vr[2];
            float l[MM] = { u0.x+v0.x, u0.y+v0.y, u0.z+v0.z, u0.w+v0.w,
                            u1.x+v1.x, u1.y+v1.y, u1.z+v1.z, u1.w+v1.w,
                            u2.x+v2.x };
            float mx = l[0];
            #pragma unroll
            for (int m = 1; m < MM; ++m) mx = fmaxf(mx, l[m]);
            float sum = 0.f;
            #pragma unroll
            for (int m = 0; m < MM; ++m) { l[m] = __expf(l[m] - mx); sum += l[m]; }
            float sc = inv / sum;
            #pragma unroll
            for (int m = 0; m < MM; ++m) q[m] = l[m] * sc;
        }
        u16* qw = qlds + (t * 16 + wave * 4 + g) * QNP + k;
        #pragma unroll
        for (int m = 0; m < MM; ++m) qw[m * 16] = f2h(q[m]);
    }

    // identity-selector B-frags for the transpose-MFMA
    f16x8 idf[2];
    #pragma unroll
    for (int s = 0; s < 2; ++s) {
        union { u16 us[8]; f16x8 v; } t;
        #pragma unroll
        for (int j = 0; j < 8; ++j)
            t.us[j] = (lhi * 8 + j == s * 16 + lr) ? (u16)0x3C00 : (u16)0;
        idf[s] = t.v;
    }

    // ---- Bload(t0) ----
    f16x8 aLo[4], aHi[4];
    f16x4 qf[4];
    #pragma unroll
    for (int g2 = 0; g2 < 4; ++g2) {
        int e = __builtin_amdgcn_ds_bpermute((g2 * 16 + lr) * 4, jjA[0]);
        int erow = ((e > 0) ? e : 1) - 1;          // pad -> row 0 (q=0 kills)
        const u16* rp = xhb + ((size_t)erow << 6) + lhi * 8;
        aLo[g2] = *(const f16x8*)(rp);
        aHi[g2] = *(const f16x8*)(rp + 32);
        qf[g2]  = *(const f16x4*)(qlds + (wave * 4 + g2) * QNP + lr * 16 + lhi * 4);
    }

    // ---- Bcomp(t0) -> slds ----
    #pragma unroll
    for (int g2 = 0; g2 < 4; ++g2) {
        const int rnode = wave * 4 + g2;
        #pragma unroll
        for (int cc = 0; cc < 4; ++cc) {
            f32x4 xt = {0.f,0.f,0.f,0.f};
            xt = __builtin_amdgcn_mfma_f32_16x16x32_f16(
                     (cc < 2) ? aLo[g2] : aHi[g2], idf[cc & 1], xt, 0, 0, 0);
            union { fp16v2 h2[2]; f16x4 h4; } at;
            at.h2[0] = __builtin_amdgcn_cvt_pkrtz(xt[0], xt[1]);
            at.h2[1] = __builtin_amdgcn_cvt_pkrtz(xt[2], xt[3]);
            f32x4 d2 = {0.f,0.f,0.f,0.f};
            d2 = __builtin_amdgcn_mfma_f32_16x16x16f16(at.h4, qf[g2], d2, 0, 0, 0);
            if (lr < 9) {
                u32 lo = __builtin_amdgcn_perm((u32)f2h(d2[1]), (u32)f2h(d2[0]), 0x05040100u);
                u32 hi = __builtin_amdgcn_perm((u32)f2h(d2[3]), (u32)f2h(d2[2]), 0x05040100u);
                uint2* p = (uint2*)(slds + rnode * SNP + lr * SCP + cc * 16 + lhi * 4);
                *p = make_uint2(lo, hi);
            }
        }
    }
    __syncthreads();

    // ---- Bload(t1): registers only — gather latency hides under C(t0) ----
    f16x8 bLo[4], bHi[4];
    f16x4 qg[4];
    #pragma unroll
    for (int g2 = 0; g2 < 4; ++g2) {
        int e = __builtin_amdgcn_ds_bpermute((g2 * 16 + lr) * 4, jjA[1]);
        int erow = ((e > 0) ? e : 1) - 1;
        const u16* rp = xhb + ((size_t)erow << 6) + lhi * 8;
        bLo[g2] = *(const f16x8*)(rp);
        bHi[g2] = *(const f16x8*)(rp + 32);
        qg[g2]  = *(const f16x4*)(qlds + (16 + wave * 4 + g2) * QNP + lr * 16 + lhi * 4);
    }

    // ---- C(t0) ----
    const int o0 = wave * 16;
    float bv = bias[o0 + lr];
    {
        f32x4 acc = {0.f,0.f,0.f,0.f};
        #pragma unroll
        for (int ks = 0; ks < NKS; ++ks) {
            int kf = ks * 32 + lhi * 8;
            int m = kf >> 6, coff = kf & 63;
            f16x8 afrag = *(const f16x8*)(slds + lr * SNP + m * SCP + coff);
            f16x8 bfrag = *(const f16x8*)(wfb2 + (size_t)(((ks * 4 + lhi) * 64) + o0 + lr) * 8);
            acc = __builtin_amdgcn_mfma_f32_16x16x32_f16(afrag, bfrag, acc, 0, 0, 0);
        }
        #pragma unroll
        for (int reg = 0; reg < 4; ++reg) {
            int rr = node0 + lhi * 4 + reg;
            out[(size_t)rr * OO + o0 + lr] = acc[reg] + bv;
        }
    }
    __syncthreads();   // all waves done reading slds(t0)

    // ---- Bcomp(t1) -> slds ----
    #pragma unroll
    for (int g2 = 0; g2 < 4; ++g2) {
        const int rnode = wave * 4 + g2;
        #pragma unroll
        for (int cc = 0; cc < 4; ++cc) {
            f32x4 xt = {0.f,0.f,0.f,0.f};
            xt = __builtin_amdgcn_mfma_f32_16x16x32_f16(
                     (cc < 2) ? bLo[g2] : bHi[g2], idf[cc & 1], xt, 0, 0, 0);
            union { fp16v2 h2[2]; f16x4 h4; } at;
            at.h2[0] = __builtin_amdgcn_cvt_pkrtz(xt[0], xt[1]);
            at.h2[1] = __builtin_amdgcn_cvt_pkrtz(xt[2], xt[3]);
            f32x4 d2 = {0.f,0.f,0.f,0.f};
            d2 = __builtin_amdgcn_mfma_f32_16x16x16f16(at.h4, qg[g2], d2, 0, 0, 0);
            if (lr < 9) {
                u32 lo = __builtin_amdgcn_perm((u32)f2h(d2[1]), (u32)f2h(d2[0]), 0x05040100u);
                u32 hi = __builtin_amdgcn_perm((u32)f2h(d2[3]), (u32)f2h(d2[2]), 0x05040100u);
                uint2* p = (uint2*)(slds + rnode * SNP + lr * SCP + cc * 16 + lhi * 4);
                *p = make_uint2(lo, hi);
            }
        }
    }
    __syncthreads();

    // ---- C(t1) ----
    {
        f32x4 acc = {0.f,0.f,0.f,0.f};
        #pragma unroll
        for (int ks = 0; ks < NKS; ++ks) {
            int kf = ks * 32 + lhi * 8;
            int m = kf >> 6, coff = kf & 63;
            f16x8 afrag = *(const f16x8*)(slds + lr * SNP + m * SCP + coff);
            f16x8 bfrag = *(const f16x8*)(wfb2 + (size_t)(((ks * 4 + lhi) * 64) + o0 + lr) * 8);
            acc = __builtin_amdgcn_mfma_f32_16x16x32_f16(afrag, bfrag, acc, 0, 0, 0);
        }
        #pragma unroll
        for (int reg = 0; reg < 4; ++reg) {
            int rr = node0 + 16 + lhi * 4 + reg;
            out[(size_t)rr * OO + o0 + lr] = acc[reg] + bv;
        }
    }
}

// ---------------------------------------------------------------------------
extern "C" void kernel_launch(void* const* d_in, const int* in_sizes, int n_in,
                              void* d_out, int out_size, void* d_ws, size_t ws_size,
                              hipStream_t stream)
{
    const float* x   = (const float*)d_in[0];
    const int*   adj = (const int*)  d_in[1];
    const float* W   = (const float*)d_in[2];
    const float* b   = (const float*)d_in[3];
    const float* u   = (const float*)d_in[4];
    const float* v   = (const float*)d_in[5];
    const float* c   = (const float*)d_in[6];
    float* out = (float*)d_out;

    // workspace layout (16B-aligned sections):
    //   uxc f32 [BN*12] | vxp f32 [BN*12] | xh f16 [BN*64] | wfb2 f16 [36864]
    //   total ~18 MB
    float* uxc = (float*)d_ws;
    float* vxp = uxc + (size_t)BN * UVP;
    u16*   xh  = (u16*)(vxp + (size_t)BN * UVP);
    u16*   wfb2= xh + (size_t)BN * CC;

    pre_kernel<<<1286, 256, 0, stream>>>(x, W, u, v, c, uxc, vxp, xh, wfb2);
    fused_kernel<<<2504, 256, 0, stream>>>(xh, adj, uxc, vxp, wfb2, b, out);
}